// Round 5
// baseline (988.957 us; speedup 1.0000x reference)
//
#include <hip/hip_runtime.h>
#include <math.h>

#define NN 20000
#define NP 20096   // padded to 157*128
#define EE 60000
#define BB 512
#define HC 1024
#define HH 4
#define CC 256

typedef _Float16 f16;
typedef f16 half8 __attribute__((ext_vector_type(8)));
typedef f16 f16x4 __attribute__((ext_vector_type(4)));
typedef float floatx4 __attribute__((ext_vector_type(4)));

__device__ __forceinline__ void load_lds16(const void* g, void* l) {
    __builtin_amdgcn_global_load_lds((const __attribute__((address_space(1))) void*)g,
                                     (__attribute__((address_space(3))) void*)l, 16, 0, 0);
}

// ---------------- precompute kernels ----------------
__global__ void ea_sum_kernel(const float* __restrict__ ea, float* sums, int E_) {
    float s0 = 0.f, s1 = 0.f, s2 = 0.f;
    for (int e = blockIdx.x * 256 + threadIdx.x; e < E_; e += gridDim.x * 256) {
        s0 += ea[e * 3 + 0];
        s1 += ea[e * 3 + 1];
        s2 += ea[e * 3 + 2];
    }
    for (int o = 32; o; o >>= 1) {
        s0 += __shfl_down(s0, o);
        s1 += __shfl_down(s1, o);
        s2 += __shfl_down(s2, o);
    }
    if ((threadIdx.x & 63) == 0) {
        atomicAdd(&sums[0], s0);
        atomicAdd(&sums[1], s1);
        atomicAdd(&sums[2], s2);
    }
}

__global__ void hist_kernel(const int* __restrict__ ei, int* counts, int E_) {
    int e = blockIdx.x * 256 + threadIdx.x;
    if (e < E_) atomicAdd(&counts[ei[E_ + e]], 1);
}

__global__ void scan_kernel(const int* __restrict__ counts, int* indptr, int n) {
    __shared__ int sdata[1024];
    int t = threadIdx.x;
    int carry = 0;
    if (t == 0) indptr[0] = 0;
    for (int base = 0; base < n; base += 1024) {
        int i = base + t;
        int v = (i < n) ? counts[i] : 0;
        sdata[t] = v;
        __syncthreads();
        for (int off = 1; off < 1024; off <<= 1) {
            int tmp = (t >= off) ? sdata[t - off] : 0;
            __syncthreads();
            sdata[t] += tmp;
            __syncthreads();
        }
        if (i < n) indptr[i + 1] = carry + sdata[t];
        int total = sdata[1023];
        __syncthreads();
        carry += total;
    }
}

__global__ void scatter_kernel(const int* __restrict__ ei, const int* __restrict__ indptr,
                               int* fill, int* sorted, int E_) {
    int e = blockIdx.x * 256 + threadIdx.x;
    if (e >= E_) return;
    int d = ei[E_ + e];
    int pos = indptr[d] + atomicAdd(&fill[d], 1);
    sorted[pos] = e;
}

__global__ void bptr_kernel(const int* __restrict__ batch, int* bptr, int n, int nb) {
    int i = blockIdx.x * 256 + threadIdx.x;
    if (i >= n) return;
    int b = batch[i];
    if (i == 0) {
        for (int bb = 0; bb <= b; bb++) bptr[bb] = 0;
    } else {
        int pb = batch[i - 1];
        if (pb != b) {
            for (int bb = pb + 1; bb <= b; bb++) bptr[bb] = i;
        }
    }
    if (i == n - 1) {
        for (int bb = b + 1; bb <= nb; bb++) bptr[bb] = n;
    }
}

// transpose+convert w_rest[3][1024][1024] fp32 -> wt[3][n][k] fp16 (B^T)
__global__ void wconv_kernel(const float* __restrict__ w_rest, f16* __restrict__ wt) {
    __shared__ float tile[64][65];
    int l = blockIdx.z;
    int bx = blockIdx.x * 64;
    int by = blockIdx.y * 64;
    int t = threadIdx.x;
    int tr = t >> 6, tc = t & 63;
#pragma unroll
    for (int i = 0; i < 16; i++) {
        int r = by + i * 4 + tr;
        tile[i * 4 + tr][tc] = w_rest[(size_t)l * 1048576 + (size_t)r * 1024 + bx + tc];
    }
    __syncthreads();
#pragma unroll
    for (int i = 0; i < 16; i++) {
        int n = bx + i * 4 + tr;
        wt[(size_t)l * 1048576 + (size_t)n * 1024 + by + tc] = (f16)tile[tc][i * 4 + tr];
    }
}

// Mmat[l][d][h]; ae_self[l][h]
__global__ void mmat_all_kernel(const float* __restrict__ w_edge,
                                const float* __restrict__ att_edge,
                                const float* __restrict__ ea_sums, float* Mmat,
                                float* ae_self, float invE) {
    __shared__ float red[256];
    __shared__ float Ms[12];
    int l = blockIdx.x;
    int t = threadIdx.x;
    for (int dh = 0; dh < 12; dh++) {
        int d = dh >> 2, hh = dh & 3;
        float v = w_edge[l * 3072 + d * HC + hh * CC + t] * att_edge[l * HC + hh * CC + t];
        red[t] = v;
        __syncthreads();
        for (int o = 128; o; o >>= 1) {
            if (t < o) red[t] += red[t + o];
            __syncthreads();
        }
        if (t == 0) {
            Ms[dh] = red[0];
            Mmat[l * 12 + dh] = red[0];
        }
        __syncthreads();
    }
    if (t < 4) {
        float v = 0.f;
        for (int d = 0; d < 3; d++) v += ea_sums[d] * invE * Ms[d * 4 + t];
        ae_self[l * 4 + t] = v;
    }
}

// pack CSR: ssrc[idx] = src node; aeh_pk[idx][l][h] = ea[eid]·M[l][:,h]
__global__ void pack_kernel(const int* __restrict__ ei, const int* __restrict__ sorted,
                            const float* __restrict__ ea, const float* __restrict__ Mmat,
                            int* __restrict__ ssrc, float* __restrict__ aeh_pk) {
    int idx = blockIdx.x * 256 + threadIdx.x;
    if (idx >= EE) return;
    int eid = sorted[idx];
    ssrc[idx] = ei[eid];
    float a0 = ea[eid * 3 + 0], a1 = ea[eid * 3 + 1], a2 = ea[eid * 3 + 2];
#pragma unroll
    for (int l = 0; l < 4; l++) {
#pragma unroll
        for (int h = 0; h < 4; h++) {
            aeh_pk[(size_t)idx * 16 + l * 4 + h] =
                a0 * Mmat[l * 12 + h] + a1 * Mmat[l * 12 + 4 + h] + a2 * Mmat[l * 12 + 8 + h];
        }
    }
}

// fold bias+BN into 2 params: out = relu(val*scale + shift)
__global__ void bnss_kernel(const float* __restrict__ bias012, const float* __restrict__ bn_g,
                            const float* __restrict__ bn_b, const float* __restrict__ bn_m,
                            const float* __restrict__ bn_v, float2* __restrict__ bnss) {
    int i = blockIdx.x * 256 + threadIdx.x;
    if (i >= 3 * HC) return;
    float s = bn_g[i] * rsqrtf(bn_v[i] + 1e-5f);
    float2 o;
    o.x = s;
    o.y = (bias012[i] - bn_m[i]) * s + bn_b[i];
    bnss[i] = o;
}

// wsv/wdv[l][k][hp]
__global__ void wvec_kernel(const float* __restrict__ w_rest, const float* __restrict__ att_src,
                            const float* __restrict__ att_dst, float* __restrict__ wsv,
                            float* __restrict__ wdv) {
    int l = blockIdx.y;
    int k = blockIdx.x;
    int t = threadIdx.x;
    int hp = t >> 6, lane = t & 63;
    int col = hp * 256 + lane * 4;
    const float* wrow = w_rest + (size_t)l * 1048576 + (size_t)k * 1024;
    float4 w4 = *(const float4*)&wrow[col];
    float4 a4 = *(const float4*)&att_src[(l + 1) * HC + col];
    float4 d4 = *(const float4*)&att_dst[(l + 1) * HC + col];
    float sp = w4.x * a4.x + w4.y * a4.y + w4.z * a4.z + w4.w * a4.w;
    float dp = w4.x * d4.x + w4.y * d4.y + w4.z * d4.z + w4.w * d4.w;
    for (int m = 1; m < 64; m <<= 1) {
        sp += __shfl_xor(sp, m);
        dp += __shfl_xor(dp, m);
    }
    if (lane == 0) {
        wsv[((size_t)l * 1024 + k) * 4 + hp] = sp;
        wdv[((size_t)l * 1024 + k) * 4 + hp] = dp;
    }
}

__global__ void w0vec_kernel(const float* __restrict__ w0, const float* __restrict__ att_src,
                             const float* __restrict__ att_dst, float* __restrict__ w0s,
                             float* __restrict__ w0d) {
    int f = blockIdx.x;
    int t = threadIdx.x;
    int hp = t >> 6, lane = t & 63;
    int col = hp * 256 + lane * 4;
    float4 w4 = *(const float4*)&w0[f * HC + col];
    float4 a4 = *(const float4*)&att_src[col];
    float4 d4 = *(const float4*)&att_dst[col];
    float sp = w4.x * a4.x + w4.y * a4.y + w4.z * a4.z + w4.w * a4.w;
    float dp = w4.x * d4.x + w4.y * d4.y + w4.z * d4.z + w4.w * d4.w;
    for (int m = 1; m < 64; m <<= 1) {
        sp += __shfl_xor(sp, m);
        dp += __shfl_xor(dp, m);
    }
    if (lane == 0) {
        w0s[f * 4 + hp] = sp;
        w0d[f * 4 + hp] = dp;
    }
}

__global__ void alpha0_kernel(const float* __restrict__ x, const float* __restrict__ w0s,
                              const float* __restrict__ w0d, float* __restrict__ asrc,
                              float* __restrict__ adst) {
    int n = blockIdx.x * 256 + threadIdx.x;
    if (n >= NN) return;
    float xr[7];
#pragma unroll
    for (int f = 0; f < 7; f++) xr[f] = x[n * 7 + f];
#pragma unroll
    for (int hp = 0; hp < 4; hp++) {
        float s = 0.f, d = 0.f;
#pragma unroll
        for (int f = 0; f < 7; f++) {
            s += xr[f] * w0s[f * 4 + hp];
            d += xr[f] * w0d[f * 4 + hp];
        }
        asrc[n * 4 + hp] = s;
        adst[n * 4 + hp] = d;
    }
}

// ---------------- GEMMs ----------------
__global__ void gemm7_kernel(const float* __restrict__ x, const float* __restrict__ w0,
                             f16* __restrict__ h16) {
    int n = blockIdx.x;
    int j = blockIdx.y * 256 + threadIdx.x;
    float acc = 0.f;
#pragma unroll
    for (int f = 0; f < 7; f++) acc += x[n * 7 + f] * w0[f * HC + j];
    h16[(size_t)n * HC + j] = (f16)acc;
}

// layers 1-3: C16 = A @ Bt^T (both padded M=NP rows). BK=64, operand-swapped MFMA so
// each lane holds 4 consecutive n-cols per reg quad -> 8B packed stores, no predicates.
// grid: x = m-blocks (157), y = n-blocks (8) -> consecutive blocks share B column in L2.
__global__ __launch_bounds__(256) void mfma_gemm_kernel(const f16* __restrict__ A,
                                                        const f16* __restrict__ Bt,
                                                        f16* __restrict__ C16,
                                                        int N, int K) {
    __shared__ f16 As[8 * 128 * 8];   // [kgroup][row][8]
    __shared__ f16 Bs[8 * 128 * 8];
    int t = threadIdx.x;
    int wave = t >> 6, lane = t & 63;
    int wr = (wave >> 1) * 64;
    int wc = (wave & 1) * 64;
    int m0 = blockIdx.x * 128;
    int n0 = blockIdx.y * 128;

    floatx4 acc[4][4];
#pragma unroll
    for (int i = 0; i < 4; i++)
#pragma unroll
        for (int j = 0; j < 4; j++) acc[i][j] = (floatx4){0.f, 0.f, 0.f, 0.f};

    const f16* pa[4];
    const f16* pb[4];
    f16* la[4];
    f16* lb[4];
#pragma unroll
    for (int is = 0; is < 4; is++) {
        int idx = is * 256 + t;
        int q = idx >> 7, r = idx & 127;
        pa[is] = A + (size_t)(m0 + r) * K + q * 8;
        pb[is] = Bt + (size_t)(n0 + r) * K + q * 8;
        la[is] = As + (size_t)idx * 8;
        lb[is] = Bs + (size_t)idx * 8;
    }

    int fq = lane >> 4, fr = lane & 15;

    for (int k0 = 0; k0 < K; k0 += 64) {
        __syncthreads();
#pragma unroll
        for (int is = 0; is < 4; is++) {
            load_lds16(pa[is] + k0, la[is]);
            load_lds16(pb[is] + k0, lb[is]);
        }
        __syncthreads();
#pragma unroll
        for (int kk = 0; kk < 2; kk++) {
            half8 af[4], bf[4];
#pragma unroll
            for (int i = 0; i < 4; i++)
                af[i] = *(const half8*)&As[((kk * 4 + fq) * 128 + wr + i * 16 + fr) * 8];
#pragma unroll
            for (int j = 0; j < 4; j++)
                bf[j] = *(const half8*)&Bs[((kk * 4 + fq) * 128 + wc + j * 16 + fr) * 8];
#pragma unroll
            for (int i = 0; i < 4; i++)
#pragma unroll
                for (int j = 0; j < 4; j++)
                    acc[i][j] = __builtin_amdgcn_mfma_f32_16x16x32_f16(bf[j], af[i],
                                                                       acc[i][j], 0, 0, 0);
        }
    }

    // swapped D layout: m-row = wr+i*16+(lane&15); n-cols = wc+j*16+(lane>>4)*4 + r
    int rr = lane & 15, cq = lane >> 4;
#pragma unroll
    for (int i = 0; i < 4; i++) {
        int row = m0 + wr + i * 16 + rr;
#pragma unroll
        for (int j = 0; j < 4; j++) {
            f16x4 o;
#pragma unroll
            for (int r = 0; r < 4; r++) o[r] = (f16)acc[i][j][r];
            *(f16x4*)&C16[(size_t)row * N + n0 + wc + j * 16 + cq * 4] = o;
        }
    }
}

// ---------------- fused attention + aggregation (one wave per node) ----------------
__global__ void agg_kernel(const f16* __restrict__ h16, const float* __restrict__ asrc,
                           const float* __restrict__ adst, const float* __restrict__ ae_self,
                           const int* __restrict__ ssrc, const float* __restrict__ aeh_pk,
                           const int* __restrict__ indptr, const float2* __restrict__ bnss,
                           const float* __restrict__ wsv, const float* __restrict__ wdv,
                           const float* __restrict__ bias3, f16* __restrict__ out16,
                           float* __restrict__ asrc_n, float* __restrict__ adst_n,
                           float* __restrict__ out3, int layer, int concat) {
    int t = threadIdx.x;
    int n = blockIdx.x * 4 + (t >> 6);
    if (n >= NN) return;
    int lane = t & 63;
    int h = lane >> 4, w16 = lane & 15;
    int col0 = h * 256 + w16 * 16;

    float adst_nh = adst[n * 4 + h];
    // self loop
    float r = asrc[n * 4 + h] + adst_nh + ae_self[layer * 4 + h];
    r = (r > 0.f) ? r : 0.2f * r;
    float p = __expf(r);
    float denom = p;
    float acc[16];
    {
        const f16* hrow = &h16[(size_t)n * HC + col0];
        half8 v0 = *(const half8*)hrow;
        half8 v1 = *(const half8*)(hrow + 8);
#pragma unroll
        for (int k = 0; k < 8; k++) {
            acc[k] = p * (float)v0[k];
            acc[8 + k] = p * (float)v1[k];
        }
    }
    int s = indptr[n], epos = indptr[n + 1];
    for (int idx = s; idx < epos; idx++) {
        int src = ssrc[idx];
        float aeh = aeh_pk[(size_t)idx * 16 + layer * 4 + h];
        float rr = asrc[src * 4 + h] + adst_nh + aeh;
        rr = (rr > 0.f) ? rr : 0.2f * rr;
        float pe = __expf(rr);
        denom += pe;
        const f16* srow = &h16[(size_t)src * HC + col0];
        half8 u0 = *(const half8*)srow;
        half8 u1 = *(const half8*)(srow + 8);
#pragma unroll
        for (int k = 0; k < 8; k++) {
            acc[k] += pe * (float)u0[k];
            acc[8 + k] += pe * (float)u1[k];
        }
    }
    float inv = 1.0f / (denom + 1e-16f);

    if (concat) {
        f16 o[16];
        float sp[4] = {0.f, 0.f, 0.f, 0.f}, dp[4] = {0.f, 0.f, 0.f, 0.f};
#pragma unroll
        for (int k = 0; k < 16; k++) {
            int col = col0 + k;
            float2 ss = bnss[col];
            float val = fmaf(acc[k] * inv, ss.x, ss.y);
            val = fmaxf(val, 0.f);
            o[k] = (f16)val;
            float4 w4s = *(const float4*)&wsv[(size_t)col * 4];
            float4 w4d = *(const float4*)&wdv[(size_t)col * 4];
            sp[0] += val * w4s.x; sp[1] += val * w4s.y;
            sp[2] += val * w4s.z; sp[3] += val * w4s.w;
            dp[0] += val * w4d.x; dp[1] += val * w4d.y;
            dp[2] += val * w4d.z; dp[3] += val * w4d.w;
        }
        f16* orow = &out16[(size_t)n * HC + col0];
        *(half8*)orow = *(half8*)&o[0];
        *(half8*)(orow + 8) = *(half8*)&o[8];
#pragma unroll
        for (int m = 1; m < 64; m <<= 1) {
#pragma unroll
            for (int j = 0; j < 4; j++) {
                sp[j] += __shfl_xor(sp[j], m);
                dp[j] += __shfl_xor(dp[j], m);
            }
        }
        if (lane == 0) {
#pragma unroll
            for (int j = 0; j < 4; j++) {
                asrc_n[n * 4 + j] = sp[j];
                adst_n[n * 4 + j] = dp[j];
            }
        }
    } else {
#pragma unroll
        for (int k = 0; k < 16; k++) {
            acc[k] *= inv;
            acc[k] += __shfl_xor(acc[k], 16);
            acc[k] += __shfl_xor(acc[k], 32);
        }
        if (h == 0) {
#pragma unroll
            for (int k = 0; k < 16; k++)
                out3[(size_t)n * CC + w16 * 16 + k] = 0.25f * acc[k] + bias3[w16 * 16 + k];
        }
    }
}

// ---------------- readout ----------------
__global__ void gate_kernel(const float* __restrict__ h3, const float* __restrict__ gw,
                            const float* __restrict__ gb, float* gate) {
    int node = blockIdx.x * 4 + (threadIdx.x >> 6);
    int lane = threadIdx.x & 63;
    if (node >= NN) return;
    const float4 hv = *(const float4*)&h3[(size_t)node * CC + lane * 4];
    const float4 w4 = *(const float4*)&gw[lane * 4];
    float s = hv.x * w4.x + hv.y * w4.y + hv.z * w4.z + hv.w * w4.w;
    for (int o = 32; o; o >>= 1) s += __shfl_down(s, o);
    if (lane == 0) gate[node] = s + gb[0];
}

__global__ void graphagg_kernel(const float* __restrict__ gate, const float* __restrict__ h3,
                                const int* __restrict__ bptr, float* __restrict__ graph) {
    __shared__ float red[256];
    __shared__ float wn[256];
    int b = blockIdx.x, t = threadIdx.x;
    int s = bptr[b], epos = bptr[b + 1];
    float m = -3.4e38f;
    for (int n = s + t; n < epos; n += 256) m = fmaxf(m, gate[n]);
    red[t] = m;
    __syncthreads();
    for (int o = 128; o; o >>= 1) {
        if (t < o) red[t] = fmaxf(red[t], red[t + o]);
        __syncthreads();
    }
    float mval = red[0];
    __syncthreads();
    float sum = 0.f;
    for (int n = s + t; n < epos; n += 256) sum += __expf(gate[n] - mval);
    red[t] = sum;
    __syncthreads();
    for (int o = 128; o; o >>= 1) {
        if (t < o) red[t] += red[t + o];
        __syncthreads();
    }
    float ssum = red[0];
    __syncthreads();
    float acc = 0.f;
    for (int base = s; base < epos; base += 256) {
        int n = base + t;
        wn[t] = (n < epos) ? __expf(gate[n] - mval) : 0.f;
        __syncthreads();
        int cnt = min(256, epos - base);
        for (int j = 0; j < cnt; j++) acc += wn[j] * h3[(size_t)(base + j) * CC + t];
        __syncthreads();
    }
    graph[b * CC + t] = acc / (ssum + 1e-16f);
}

__global__ void proj_kernel(const float* __restrict__ graph, const float* __restrict__ pw,
                            const float* __restrict__ pb, float* __restrict__ out) {
    __shared__ float g[256];
    int b = blockIdx.x, t = threadIdx.x;
    g[t] = graph[b * CC + t];
    __syncthreads();
    for (int j = t; j < 1024; j += 256) {
        float acc = pb[j];
        for (int c = 0; c < 256; c++) acc += g[c] * pw[c * 1024 + j];
        out[(size_t)b * 1024 + j] = acc;
    }
}

// ---------------- host ----------------
extern "C" void kernel_launch(void* const* d_in, const int* in_sizes, int n_in,
                              void* d_out, int out_size, void* d_ws, size_t ws_size,
                              hipStream_t stream) {
    const float* x = (const float*)d_in[0];
    const int* ei = (const int*)d_in[1];
    const float* ea = (const float*)d_in[2];
    const int* batch = (const int*)d_in[3];
    const float* w0 = (const float*)d_in[4];
    const float* w_rest = (const float*)d_in[5];
    const float* w_edge = (const float*)d_in[6];
    const float* att_src = (const float*)d_in[7];
    const float* att_dst = (const float*)d_in[8];
    const float* att_edge = (const float*)d_in[9];
    const float* bias012 = (const float*)d_in[10];
    const float* bias3 = (const float*)d_in[11];
    const float* bn_g = (const float*)d_in[12];
    const float* bn_b = (const float*)d_in[13];
    const float* bn_m = (const float*)d_in[14];
    const float* bn_v = (const float*)d_in[15];
    const float* gate_w = (const float*)d_in[16];
    const float* gate_b = (const float*)d_in[17];
    const float* proj_w = (const float*)d_in[18];
    const float* proj_b = (const float*)d_in[19];
    float* out = (float*)d_out;

    float* ws = (float*)d_ws;
    size_t off = 0;
    f16* h_lin = (f16*)(ws + off); off += (size_t)NP * HC / 2;   // GEMM output (padded M)
    f16* h_in = (f16*)(ws + off); off += (size_t)NP * HC / 2;    // agg output / GEMM input
    float* h3 = ws + off; off += (size_t)NN * CC;
    f16* wt = (f16*)(ws + off); off += (size_t)3 * HC * HC / 2;  // W^T fp16
    float* asrcA = ws + off; off += (size_t)NN * 4;
    float* adstA = ws + off; off += (size_t)NN * 4;
    float* asrcB = ws + off; off += (size_t)NN * 4;
    float* adstB = ws + off; off += (size_t)NN * 4;
    float* wsv = ws + off; off += (size_t)3 * HC * 4;
    float* wdv = ws + off; off += (size_t)3 * HC * 4;
    float* w0s = ws + off; off += 28;
    float* w0d = ws + off; off += 28;
    float2* bnss = (float2*)(ws + off); off += (size_t)3 * HC * 2;
    float* aeh_pk = ws + off; off += (size_t)EE * 16;
    float* gate = ws + off; off += (size_t)NN;
    float* graph = ws + off; off += (size_t)BB * CC;
    float* ea_sums = ws + off; off += 4;
    float* Mmat = ws + off; off += 48;
    float* ae_self = ws + off; off += 16;
    int* counts = (int*)(ws + off); off += NN;
    int* indptr = (int*)(ws + off); off += NN + 1;
    int* fill = (int*)(ws + off); off += NN;
    int* sorted = (int*)(ws + off); off += EE;
    int* ssrc = (int*)(ws + off); off += EE;
    int* bptr = (int*)(ws + off); off += BB + 1;

    hipMemsetAsync(ea_sums, 0, 4 * sizeof(float), stream);
    hipMemsetAsync(counts, 0, NN * sizeof(int), stream);
    hipMemsetAsync(fill, 0, NN * sizeof(int), stream);

    ea_sum_kernel<<<64, 256, 0, stream>>>(ea, ea_sums, EE);
    hist_kernel<<<(EE + 255) / 256, 256, 0, stream>>>(ei, counts, EE);
    scan_kernel<<<1, 1024, 0, stream>>>(counts, indptr, NN);
    scatter_kernel<<<(EE + 255) / 256, 256, 0, stream>>>(ei, indptr, fill, sorted, EE);
    bptr_kernel<<<(NN + 255) / 256, 256, 0, stream>>>(batch, bptr, NN, BB);
    wconv_kernel<<<dim3(16, 16, 3), 256, 0, stream>>>(w_rest, wt);
    mmat_all_kernel<<<4, 256, 0, stream>>>(w_edge, att_edge, ea_sums, Mmat, ae_self,
                                           1.0f / EE);
    pack_kernel<<<(EE + 255) / 256, 256, 0, stream>>>(ei, sorted, ea, Mmat, ssrc, aeh_pk);
    bnss_kernel<<<(3 * HC + 255) / 256, 256, 0, stream>>>(bias012, bn_g, bn_b, bn_m, bn_v,
                                                          bnss);
    wvec_kernel<<<dim3(1024, 3), 256, 0, stream>>>(w_rest, att_src, att_dst, wsv, wdv);
    w0vec_kernel<<<7, 256, 0, stream>>>(w0, att_src, att_dst, w0s, w0d);
    alpha0_kernel<<<(NN + 255) / 256, 256, 0, stream>>>(x, w0s, w0d, asrcA, adstA);

    float* asrc_cur = asrcA;
    float* adst_cur = adstA;
    float* asrc_nxt = asrcB;
    float* adst_nxt = adstB;
    for (int i = 0; i < 4; i++) {
        if (i == 0) {
            gemm7_kernel<<<dim3(NN, 4), 256, 0, stream>>>(x, w0, h_lin);
        } else {
            mfma_gemm_kernel<<<dim3(NP / 128, HC / 128), 256, 0, stream>>>(
                h_in, wt + (size_t)(i - 1) * HC * HC, h_lin, HC, HC);
        }
        agg_kernel<<<(NN + 3) / 4, 256, 0, stream>>>(
            h_lin, asrc_cur, adst_cur, ae_self, ssrc, aeh_pk, indptr, bnss + (size_t)i * HC,
            wsv + (size_t)i * HC * 4, wdv + (size_t)i * HC * 4, bias3, h_in, asrc_nxt,
            adst_nxt, h3, i, (i < 3) ? 1 : 0);
        float* tmp = asrc_cur; asrc_cur = asrc_nxt; asrc_nxt = tmp;
        tmp = adst_cur; adst_cur = adst_nxt; adst_nxt = tmp;
    }

    gate_kernel<<<(NN + 3) / 4, 256, 0, stream>>>(h3, gate_w, gate_b, gate);
    graphagg_kernel<<<BB, 256, 0, stream>>>(gate, h3, bptr, graph);
    proj_kernel<<<BB, 256, 0, stream>>>(graph, proj_w, proj_b, out);
}

// Round 6
// 952.013 us; speedup vs baseline: 1.0388x; 1.0388x over previous
//
#include <hip/hip_runtime.h>
#include <math.h>

#define NN 20000
#define NP 20096   // padded to 157*128
#define EE 60000
#define BB 512
#define HC 1024
#define HH 4
#define CC 256

typedef _Float16 f16;
typedef f16 half8 __attribute__((ext_vector_type(8)));
typedef f16 f16x4 __attribute__((ext_vector_type(4)));
typedef float floatx4 __attribute__((ext_vector_type(4)));

__device__ __forceinline__ void load_lds16(const void* g, void* l) {
    __builtin_amdgcn_global_load_lds((const __attribute__((address_space(1))) void*)g,
                                     (__attribute__((address_space(3))) void*)l, 16, 0, 0);
}

// ---------------- precompute kernels ----------------
__global__ void ea_sum_kernel(const float* __restrict__ ea, float* sums, int E_) {
    float s0 = 0.f, s1 = 0.f, s2 = 0.f;
    for (int e = blockIdx.x * 256 + threadIdx.x; e < E_; e += gridDim.x * 256) {
        s0 += ea[e * 3 + 0];
        s1 += ea[e * 3 + 1];
        s2 += ea[e * 3 + 2];
    }
    for (int o = 32; o; o >>= 1) {
        s0 += __shfl_down(s0, o);
        s1 += __shfl_down(s1, o);
        s2 += __shfl_down(s2, o);
    }
    if ((threadIdx.x & 63) == 0) {
        atomicAdd(&sums[0], s0);
        atomicAdd(&sums[1], s1);
        atomicAdd(&sums[2], s2);
    }
}

__global__ void hist_kernel(const int* __restrict__ ei, int* counts, int E_) {
    int e = blockIdx.x * 256 + threadIdx.x;
    if (e < E_) atomicAdd(&counts[ei[E_ + e]], 1);
}

__global__ void scan_kernel(const int* __restrict__ counts, int* indptr, int n) {
    __shared__ int sdata[1024];
    int t = threadIdx.x;
    int carry = 0;
    if (t == 0) indptr[0] = 0;
    for (int base = 0; base < n; base += 1024) {
        int i = base + t;
        int v = (i < n) ? counts[i] : 0;
        sdata[t] = v;
        __syncthreads();
        for (int off = 1; off < 1024; off <<= 1) {
            int tmp = (t >= off) ? sdata[t - off] : 0;
            __syncthreads();
            sdata[t] += tmp;
            __syncthreads();
        }
        if (i < n) indptr[i + 1] = carry + sdata[t];
        int total = sdata[1023];
        __syncthreads();
        carry += total;
    }
}

__global__ void scatter_kernel(const int* __restrict__ ei, const int* __restrict__ indptr,
                               int* fill, int* sorted, int E_) {
    int e = blockIdx.x * 256 + threadIdx.x;
    if (e >= E_) return;
    int d = ei[E_ + e];
    int pos = indptr[d] + atomicAdd(&fill[d], 1);
    sorted[pos] = e;
}

__global__ void bptr_kernel(const int* __restrict__ batch, int* bptr, int n, int nb) {
    int i = blockIdx.x * 256 + threadIdx.x;
    if (i >= n) return;
    int b = batch[i];
    if (i == 0) {
        for (int bb = 0; bb <= b; bb++) bptr[bb] = 0;
    } else {
        int pb = batch[i - 1];
        if (pb != b) {
            for (int bb = pb + 1; bb <= b; bb++) bptr[bb] = i;
        }
    }
    if (i == n - 1) {
        for (int bb = b + 1; bb <= nb; bb++) bptr[bb] = n;
    }
}

// transpose+convert w_rest[3][1024][1024] fp32 -> wt[3][n][k] fp16 (B^T)
__global__ void wconv_kernel(const float* __restrict__ w_rest, f16* __restrict__ wt) {
    __shared__ float tile[64][65];
    int l = blockIdx.z;
    int bx = blockIdx.x * 64;
    int by = blockIdx.y * 64;
    int t = threadIdx.x;
    int tr = t >> 6, tc = t & 63;
#pragma unroll
    for (int i = 0; i < 16; i++) {
        int r = by + i * 4 + tr;
        tile[i * 4 + tr][tc] = w_rest[(size_t)l * 1048576 + (size_t)r * 1024 + bx + tc];
    }
    __syncthreads();
#pragma unroll
    for (int i = 0; i < 16; i++) {
        int n = bx + i * 4 + tr;
        wt[(size_t)l * 1048576 + (size_t)n * 1024 + by + tc] = (f16)tile[tc][i * 4 + tr];
    }
}

// Mmat[l][d][h]; ae_self[l][h]
__global__ void mmat_all_kernel(const float* __restrict__ w_edge,
                                const float* __restrict__ att_edge,
                                const float* __restrict__ ea_sums, float* Mmat,
                                float* ae_self, float invE) {
    __shared__ float red[256];
    __shared__ float Ms[12];
    int l = blockIdx.x;
    int t = threadIdx.x;
    for (int dh = 0; dh < 12; dh++) {
        int d = dh >> 2, hh = dh & 3;
        float v = w_edge[l * 3072 + d * HC + hh * CC + t] * att_edge[l * HC + hh * CC + t];
        red[t] = v;
        __syncthreads();
        for (int o = 128; o; o >>= 1) {
            if (t < o) red[t] += red[t + o];
            __syncthreads();
        }
        if (t == 0) {
            Ms[dh] = red[0];
            Mmat[l * 12 + dh] = red[0];
        }
        __syncthreads();
    }
    if (t < 4) {
        float v = 0.f;
        for (int d = 0; d < 3; d++) v += ea_sums[d] * invE * Ms[d * 4 + t];
        ae_self[l * 4 + t] = v;
    }
}

// pack CSR: ssrc[idx] = src node; aeh_pk[idx][l][h] = ea[eid]·M[l][:,h]
__global__ void pack_kernel(const int* __restrict__ ei, const int* __restrict__ sorted,
                            const float* __restrict__ ea, const float* __restrict__ Mmat,
                            int* __restrict__ ssrc, float* __restrict__ aeh_pk) {
    int idx = blockIdx.x * 256 + threadIdx.x;
    if (idx >= EE) return;
    int eid = sorted[idx];
    ssrc[idx] = ei[eid];
    float a0 = ea[eid * 3 + 0], a1 = ea[eid * 3 + 1], a2 = ea[eid * 3 + 2];
#pragma unroll
    for (int l = 0; l < 4; l++) {
#pragma unroll
        for (int h = 0; h < 4; h++) {
            aeh_pk[(size_t)idx * 16 + l * 4 + h] =
                a0 * Mmat[l * 12 + h] + a1 * Mmat[l * 12 + 4 + h] + a2 * Mmat[l * 12 + 8 + h];
        }
    }
}

// per-layer edge-parallel: q[idx][h] = asrc[src][h] + aeh_pk[idx][layer][h]
__global__ void edgep_kernel(const int* __restrict__ ssrc, const float* __restrict__ aeh_pk,
                             const float* __restrict__ asrc, float* __restrict__ q,
                             int layer) {
    int i = blockIdx.x * 256 + threadIdx.x;
    if (i >= EE) return;
    int src = ssrc[i];
    float4 a = *(const float4*)&asrc[(size_t)src * 4];
    float4 m = *(const float4*)&aeh_pk[(size_t)i * 16 + layer * 4];
    float4 o;
    o.x = a.x + m.x;
    o.y = a.y + m.y;
    o.z = a.z + m.z;
    o.w = a.w + m.w;
    *(float4*)&q[(size_t)i * 4] = o;
}

// fold bias+BN into 2 params: out = relu(val*scale + shift)
__global__ void bnss_kernel(const float* __restrict__ bias012, const float* __restrict__ bn_g,
                            const float* __restrict__ bn_b, const float* __restrict__ bn_m,
                            const float* __restrict__ bn_v, float2* __restrict__ bnss) {
    int i = blockIdx.x * 256 + threadIdx.x;
    if (i >= 3 * HC) return;
    float s = bn_g[i] * rsqrtf(bn_v[i] + 1e-5f);
    float2 o;
    o.x = s;
    o.y = (bias012[i] - bn_m[i]) * s + bn_b[i];
    bnss[i] = o;
}

// wsv/wdv[l][k][hp]
__global__ void wvec_kernel(const float* __restrict__ w_rest, const float* __restrict__ att_src,
                            const float* __restrict__ att_dst, float* __restrict__ wsv,
                            float* __restrict__ wdv) {
    int l = blockIdx.y;
    int k = blockIdx.x;
    int t = threadIdx.x;
    int hp = t >> 6, lane = t & 63;
    int col = hp * 256 + lane * 4;
    const float* wrow = w_rest + (size_t)l * 1048576 + (size_t)k * 1024;
    float4 w4 = *(const float4*)&wrow[col];
    float4 a4 = *(const float4*)&att_src[(l + 1) * HC + col];
    float4 d4 = *(const float4*)&att_dst[(l + 1) * HC + col];
    float sp = w4.x * a4.x + w4.y * a4.y + w4.z * a4.z + w4.w * a4.w;
    float dp = w4.x * d4.x + w4.y * d4.y + w4.z * d4.z + w4.w * d4.w;
    for (int m = 1; m < 64; m <<= 1) {
        sp += __shfl_xor(sp, m);
        dp += __shfl_xor(dp, m);
    }
    if (lane == 0) {
        wsv[((size_t)l * 1024 + k) * 4 + hp] = sp;
        wdv[((size_t)l * 1024 + k) * 4 + hp] = dp;
    }
}

__global__ void w0vec_kernel(const float* __restrict__ w0, const float* __restrict__ att_src,
                             const float* __restrict__ att_dst, float* __restrict__ w0s,
                             float* __restrict__ w0d) {
    int f = blockIdx.x;
    int t = threadIdx.x;
    int hp = t >> 6, lane = t & 63;
    int col = hp * 256 + lane * 4;
    float4 w4 = *(const float4*)&w0[f * HC + col];
    float4 a4 = *(const float4*)&att_src[col];
    float4 d4 = *(const float4*)&att_dst[col];
    float sp = w4.x * a4.x + w4.y * a4.y + w4.z * a4.z + w4.w * a4.w;
    float dp = w4.x * d4.x + w4.y * d4.y + w4.z * d4.z + w4.w * d4.w;
    for (int m = 1; m < 64; m <<= 1) {
        sp += __shfl_xor(sp, m);
        dp += __shfl_xor(dp, m);
    }
    if (lane == 0) {
        w0s[f * 4 + hp] = sp;
        w0d[f * 4 + hp] = dp;
    }
}

__global__ void alpha0_kernel(const float* __restrict__ x, const float* __restrict__ w0s,
                              const float* __restrict__ w0d, float* __restrict__ asrc,
                              float* __restrict__ adst) {
    int n = blockIdx.x * 256 + threadIdx.x;
    if (n >= NN) return;
    float xr[7];
#pragma unroll
    for (int f = 0; f < 7; f++) xr[f] = x[n * 7 + f];
#pragma unroll
    for (int hp = 0; hp < 4; hp++) {
        float s = 0.f, d = 0.f;
#pragma unroll
        for (int f = 0; f < 7; f++) {
            s += xr[f] * w0s[f * 4 + hp];
            d += xr[f] * w0d[f * 4 + hp];
        }
        asrc[n * 4 + hp] = s;
        adst[n * 4 + hp] = d;
    }
}

// ---------------- GEMMs ----------------
__global__ void gemm7_kernel(const float* __restrict__ x, const float* __restrict__ w0,
                             f16* __restrict__ h16) {
    int n = blockIdx.x;
    int j = blockIdx.y * 256 + threadIdx.x;
    float acc = 0.f;
#pragma unroll
    for (int f = 0; f < 7; f++) acc += x[n * 7 + f] * w0[f * HC + j];
    h16[(size_t)n * HC + j] = (f16)acc;
}

// layers 1-3: C16 = A @ Bt^T (padded M=NP rows, no predicates). BK=32, 16KB LDS
// (known-good R4 loop) + operand-swapped MFMA epilogue -> 8B packed stores.
__global__ __launch_bounds__(256) void mfma_gemm_kernel(const f16* __restrict__ A,
                                                        const f16* __restrict__ Bt,
                                                        f16* __restrict__ C16,
                                                        int N, int K) {
    __shared__ f16 As[4 * 128 * 8];
    __shared__ f16 Bs[4 * 128 * 8];
    int t = threadIdx.x;
    int wave = t >> 6, lane = t & 63;
    int wr = (wave >> 1) * 64;
    int wc = (wave & 1) * 64;
    int m0 = blockIdx.x * 128;
    int n0 = blockIdx.y * 128;

    floatx4 acc[4][4];
#pragma unroll
    for (int i = 0; i < 4; i++)
#pragma unroll
        for (int j = 0; j < 4; j++) acc[i][j] = (floatx4){0.f, 0.f, 0.f, 0.f};

    int q0 = t >> 7, r0 = t & 127;
    int q1 = (256 + t) >> 7, r1 = (256 + t) & 127;
    const f16* pa0 = A + (size_t)(m0 + r0) * K + q0 * 8;
    const f16* pa1 = A + (size_t)(m0 + r1) * K + q1 * 8;
    const f16* pb0 = Bt + (size_t)(n0 + r0) * K + q0 * 8;
    const f16* pb1 = Bt + (size_t)(n0 + r1) * K + q1 * 8;
    f16* la0 = As + (size_t)t * 8;
    f16* la1 = As + (size_t)(256 + t) * 8;
    f16* lb0 = Bs + (size_t)t * 8;
    f16* lb1 = Bs + (size_t)(256 + t) * 8;

    int fq = lane >> 4, fr = lane & 15;
    int aoff[4], boff[4];
#pragma unroll
    for (int i = 0; i < 4; i++) {
        aoff[i] = (fq * 128 + wr + i * 16 + fr) * 8;
        boff[i] = (fq * 128 + wc + i * 16 + fr) * 8;
    }

    for (int k0 = 0; k0 < K; k0 += 32) {
        __syncthreads();
        load_lds16(pa0 + k0, la0);
        load_lds16(pa1 + k0, la1);
        load_lds16(pb0 + k0, lb0);
        load_lds16(pb1 + k0, lb1);
        __syncthreads();
        half8 af[4], bf[4];
#pragma unroll
        for (int i = 0; i < 4; i++) af[i] = *(const half8*)&As[aoff[i]];
#pragma unroll
        for (int j = 0; j < 4; j++) bf[j] = *(const half8*)&Bs[boff[j]];
#pragma unroll
        for (int i = 0; i < 4; i++)
#pragma unroll
            for (int j = 0; j < 4; j++)
                acc[i][j] = __builtin_amdgcn_mfma_f32_16x16x32_f16(bf[j], af[i], acc[i][j],
                                                                   0, 0, 0);
    }

    // swapped D layout: m-row = wr+i*16+(lane&15); n-cols = wc+j*16+(lane>>4)*4+r
    int rr = lane & 15, cq = lane >> 4;
#pragma unroll
    for (int i = 0; i < 4; i++) {
        int row = m0 + wr + i * 16 + rr;
#pragma unroll
        for (int j = 0; j < 4; j++) {
            f16x4 o;
#pragma unroll
            for (int r = 0; r < 4; r++) o[r] = (f16)acc[i][j][r];
            *(f16x4*)&C16[(size_t)row * N + n0 + wc + j * 16 + cq * 4] = o;
        }
    }
}

// ---------------- fused attention + aggregation ----------------
// Wave per node, chunk-of-4 edge pipeline: ssrc/q loads first, then all 8
// independent row loads in flight, then accumulate. Tail guard q=-1e9 -> pe=0.
__global__ void agg_kernel(const f16* __restrict__ h16, const float* __restrict__ asrc,
                           const float* __restrict__ adst, const float* __restrict__ ae_self,
                           const int* __restrict__ ssrc, const float* __restrict__ q,
                           const int* __restrict__ indptr, const float2* __restrict__ bnss,
                           const float* __restrict__ wsv, const float* __restrict__ wdv,
                           const float* __restrict__ bias3, f16* __restrict__ out16,
                           float* __restrict__ asrc_n, float* __restrict__ adst_n,
                           float* __restrict__ out3, int layer, int concat) {
    int t = threadIdx.x;
    int n = blockIdx.x * 4 + (t >> 6);
    if (n >= NN) return;
    int lane = t & 63;
    int h = lane >> 4, w16 = lane & 15;
    int col0 = h * 256 + w16 * 16;

    float adst_nh = adst[n * 4 + h];
    float r = asrc[n * 4 + h] + adst_nh + ae_self[layer * 4 + h];
    r = (r > 0.f) ? r : 0.2f * r;
    float p = __expf(r);
    float denom = p;
    float acc[16];
    {
        const f16* hrow = &h16[(size_t)n * HC + col0];
        half8 v0 = *(const half8*)hrow;
        half8 v1 = *(const half8*)(hrow + 8);
#pragma unroll
        for (int k = 0; k < 8; k++) {
            acc[k] = p * (float)v0[k];
            acc[8 + k] = p * (float)v1[k];
        }
    }
    int s = indptr[n], epos = indptr[n + 1];
    for (int base = s; base < epos; base += 4) {
        int rem = epos - base;
        int src[4];
        float qv[4];
#pragma unroll
        for (int j = 0; j < 4; j++) {
            if (j < rem) {
                src[j] = ssrc[base + j];
                qv[j] = q[(size_t)(base + j) * 4 + h];
            } else {
                src[j] = n;
                qv[j] = -1e9f;
            }
        }
        half8 u0[4], u1[4];
#pragma unroll
        for (int j = 0; j < 4; j++) {
            const f16* srow = &h16[(size_t)src[j] * HC + col0];
            u0[j] = *(const half8*)srow;
            u1[j] = *(const half8*)(srow + 8);
        }
#pragma unroll
        for (int j = 0; j < 4; j++) {
            float rr = qv[j] + adst_nh;
            rr = (rr > 0.f) ? rr : 0.2f * rr;
            float pe = __expf(rr);
            denom += pe;
#pragma unroll
            for (int k = 0; k < 8; k++) {
                acc[k] += pe * (float)u0[j][k];
                acc[8 + k] += pe * (float)u1[j][k];
            }
        }
    }
    float inv = 1.0f / (denom + 1e-16f);

    if (concat) {
        f16 o[16];
        float sp[4] = {0.f, 0.f, 0.f, 0.f}, dp[4] = {0.f, 0.f, 0.f, 0.f};
#pragma unroll
        for (int k = 0; k < 16; k++) {
            int col = col0 + k;
            float2 ss = bnss[col];
            float val = fmaf(acc[k] * inv, ss.x, ss.y);
            val = fmaxf(val, 0.f);
            o[k] = (f16)val;
            float4 w4s = *(const float4*)&wsv[(size_t)col * 4];
            float4 w4d = *(const float4*)&wdv[(size_t)col * 4];
            sp[0] += val * w4s.x; sp[1] += val * w4s.y;
            sp[2] += val * w4s.z; sp[3] += val * w4s.w;
            dp[0] += val * w4d.x; dp[1] += val * w4d.y;
            dp[2] += val * w4d.z; dp[3] += val * w4d.w;
        }
        f16* orow = &out16[(size_t)n * HC + col0];
        *(half8*)orow = *(half8*)&o[0];
        *(half8*)(orow + 8) = *(half8*)&o[8];
#pragma unroll
        for (int m = 1; m < 64; m <<= 1) {
#pragma unroll
            for (int j = 0; j < 4; j++) {
                sp[j] += __shfl_xor(sp[j], m);
                dp[j] += __shfl_xor(dp[j], m);
            }
        }
        if (lane == 0) {
#pragma unroll
            for (int j = 0; j < 4; j++) {
                asrc_n[n * 4 + j] = sp[j];
                adst_n[n * 4 + j] = dp[j];
            }
        }
    } else {
#pragma unroll
        for (int k = 0; k < 16; k++) {
            acc[k] *= inv;
            acc[k] += __shfl_xor(acc[k], 16);
            acc[k] += __shfl_xor(acc[k], 32);
        }
        if (h == 0) {
#pragma unroll
            for (int k = 0; k < 16; k++)
                out3[(size_t)n * CC + w16 * 16 + k] = 0.25f * acc[k] + bias3[w16 * 16 + k];
        }
    }
}

// ---------------- readout ----------------
__global__ void gate_kernel(const float* __restrict__ h3, const float* __restrict__ gw,
                            const float* __restrict__ gb, float* gate) {
    int node = blockIdx.x * 4 + (threadIdx.x >> 6);
    int lane = threadIdx.x & 63;
    if (node >= NN) return;
    const float4 hv = *(const float4*)&h3[(size_t)node * CC + lane * 4];
    const float4 w4 = *(const float4*)&gw[lane * 4];
    float s = hv.x * w4.x + hv.y * w4.y + hv.z * w4.z + hv.w * w4.w;
    for (int o = 32; o; o >>= 1) s += __shfl_down(s, o);
    if (lane == 0) gate[node] = s + gb[0];
}

__global__ void graphagg_kernel(const float* __restrict__ gate, const float* __restrict__ h3,
                                const int* __restrict__ bptr, float* __restrict__ graph) {
    __shared__ float red[256];
    __shared__ float wn[256];
    int b = blockIdx.x, t = threadIdx.x;
    int s = bptr[b], epos = bptr[b + 1];
    float m = -3.4e38f;
    for (int n = s + t; n < epos; n += 256) m = fmaxf(m, gate[n]);
    red[t] = m;
    __syncthreads();
    for (int o = 128; o; o >>= 1) {
        if (t < o) red[t] = fmaxf(red[t], red[t + o]);
        __syncthreads();
    }
    float mval = red[0];
    __syncthreads();
    float sum = 0.f;
    for (int n = s + t; n < epos; n += 256) sum += __expf(gate[n] - mval);
    red[t] = sum;
    __syncthreads();
    for (int o = 128; o; o >>= 1) {
        if (t < o) red[t] += red[t + o];
        __syncthreads();
    }
    float ssum = red[0];
    __syncthreads();
    float acc = 0.f;
    for (int base = s; base < epos; base += 256) {
        int n = base + t;
        wn[t] = (n < epos) ? __expf(gate[n] - mval) : 0.f;
        __syncthreads();
        int cnt = min(256, epos - base);
        for (int j = 0; j < cnt; j++) acc += wn[j] * h3[(size_t)(base + j) * CC + t];
        __syncthreads();
    }
    graph[b * CC + t] = acc / (ssum + 1e-16f);
}

__global__ void proj_kernel(const float* __restrict__ graph, const float* __restrict__ pw,
                            const float* __restrict__ pb, float* __restrict__ out) {
    __shared__ float g[256];
    int b = blockIdx.x, t = threadIdx.x;
    g[t] = graph[b * CC + t];
    __syncthreads();
    for (int j = t; j < 1024; j += 256) {
        float acc = pb[j];
        for (int c = 0; c < 256; c++) acc += g[c] * pw[c * 1024 + j];
        out[(size_t)b * 1024 + j] = acc;
    }
}

// ---------------- host ----------------
extern "C" void kernel_launch(void* const* d_in, const int* in_sizes, int n_in,
                              void* d_out, int out_size, void* d_ws, size_t ws_size,
                              hipStream_t stream) {
    const float* x = (const float*)d_in[0];
    const int* ei = (const int*)d_in[1];
    const float* ea = (const float*)d_in[2];
    const int* batch = (const int*)d_in[3];
    const float* w0 = (const float*)d_in[4];
    const float* w_rest = (const float*)d_in[5];
    const float* w_edge = (const float*)d_in[6];
    const float* att_src = (const float*)d_in[7];
    const float* att_dst = (const float*)d_in[8];
    const float* att_edge = (const float*)d_in[9];
    const float* bias012 = (const float*)d_in[10];
    const float* bias3 = (const float*)d_in[11];
    const float* bn_g = (const float*)d_in[12];
    const float* bn_b = (const float*)d_in[13];
    const float* bn_m = (const float*)d_in[14];
    const float* bn_v = (const float*)d_in[15];
    const float* gate_w = (const float*)d_in[16];
    const float* gate_b = (const float*)d_in[17];
    const float* proj_w = (const float*)d_in[18];
    const float* proj_b = (const float*)d_in[19];
    float* out = (float*)d_out;

    float* ws = (float*)d_ws;
    size_t off = 0;
    f16* h_lin = (f16*)(ws + off); off += (size_t)NP * HC / 2;
    f16* h_in = (f16*)(ws + off); off += (size_t)NP * HC / 2;
    float* h3 = ws + off; off += (size_t)NN * CC;
    f16* wt = (f16*)(ws + off); off += (size_t)3 * HC * HC / 2;
    float* asrcA = ws + off; off += (size_t)NN * 4;
    float* adstA = ws + off; off += (size_t)NN * 4;
    float* asrcB = ws + off; off += (size_t)NN * 4;
    float* adstB = ws + off; off += (size_t)NN * 4;
    float* wsv = ws + off; off += (size_t)3 * HC * 4;
    float* wdv = ws + off; off += (size_t)3 * HC * 4;
    float* w0s = ws + off; off += 28;
    float* w0d = ws + off; off += 28;
    float2* bnss = (float2*)(ws + off); off += (size_t)3 * HC * 2;
    float* aeh_pk = ws + off; off += (size_t)EE * 16;
    float* qbuf = ws + off; off += (size_t)EE * 4;
    float* gate = ws + off; off += (size_t)NN;
    float* graph = ws + off; off += (size_t)BB * CC;
    float* ea_sums = ws + off; off += 4;
    float* Mmat = ws + off; off += 48;
    float* ae_self = ws + off; off += 16;
    int* counts = (int*)(ws + off); off += NN;
    int* indptr = (int*)(ws + off); off += NN + 1;
    int* fill = (int*)(ws + off); off += NN;
    int* sorted = (int*)(ws + off); off += EE;
    int* ssrc = (int*)(ws + off); off += EE;
    int* bptr = (int*)(ws + off); off += BB + 1;

    hipMemsetAsync(ea_sums, 0, 4 * sizeof(float), stream);
    hipMemsetAsync(counts, 0, NN * sizeof(int), stream);
    hipMemsetAsync(fill, 0, NN * sizeof(int), stream);

    ea_sum_kernel<<<64, 256, 0, stream>>>(ea, ea_sums, EE);
    hist_kernel<<<(EE + 255) / 256, 256, 0, stream>>>(ei, counts, EE);
    scan_kernel<<<1, 1024, 0, stream>>>(counts, indptr, NN);
    scatter_kernel<<<(EE + 255) / 256, 256, 0, stream>>>(ei, indptr, fill, sorted, EE);
    bptr_kernel<<<(NN + 255) / 256, 256, 0, stream>>>(batch, bptr, NN, BB);
    wconv_kernel<<<dim3(16, 16, 3), 256, 0, stream>>>(w_rest, wt);
    mmat_all_kernel<<<4, 256, 0, stream>>>(w_edge, att_edge, ea_sums, Mmat, ae_self,
                                           1.0f / EE);
    pack_kernel<<<(EE + 255) / 256, 256, 0, stream>>>(ei, sorted, ea, Mmat, ssrc, aeh_pk);
    bnss_kernel<<<(3 * HC + 255) / 256, 256, 0, stream>>>(bias012, bn_g, bn_b, bn_m, bn_v,
                                                          bnss);
    wvec_kernel<<<dim3(1024, 3), 256, 0, stream>>>(w_rest, att_src, att_dst, wsv, wdv);
    w0vec_kernel<<<7, 256, 0, stream>>>(w0, att_src, att_dst, w0s, w0d);
    alpha0_kernel<<<(NN + 255) / 256, 256, 0, stream>>>(x, w0s, w0d, asrcA, adstA);

    float* asrc_cur = asrcA;
    float* adst_cur = adstA;
    float* asrc_nxt = asrcB;
    float* adst_nxt = adstB;
    for (int i = 0; i < 4; i++) {
        if (i == 0) {
            gemm7_kernel<<<dim3(NN, 4), 256, 0, stream>>>(x, w0, h_lin);
        } else {
            mfma_gemm_kernel<<<dim3(NP / 128, HC / 128), 256, 0, stream>>>(
                h_in, wt + (size_t)(i - 1) * HC * HC, h_lin, HC, HC);
        }
        edgep_kernel<<<(EE + 255) / 256, 256, 0, stream>>>(ssrc, aeh_pk, asrc_cur, qbuf, i);
        agg_kernel<<<(NN + 3) / 4, 256, 0, stream>>>(
            h_lin, asrc_cur, adst_cur, ae_self, ssrc, qbuf, indptr, bnss + (size_t)i * HC,
            wsv + (size_t)i * HC * 4, wdv + (size_t)i * HC * 4, bias3, h_in, asrc_nxt,
            adst_nxt, h3, i, (i < 3) ? 1 : 0);
        float* tmp = asrc_cur; asrc_cur = asrc_nxt; asrc_nxt = tmp;
        tmp = adst_cur; adst_cur = adst_nxt; adst_nxt = tmp;
    }

    gate_kernel<<<(NN + 3) / 4, 256, 0, stream>>>(h3, gate_w, gate_b, gate);
    graphagg_kernel<<<BB, 256, 0, stream>>>(gate, h3, bptr, graph);
    proj_kernel<<<BB, 256, 0, stream>>>(graph, proj_w, proj_b, out);
}

// Round 7
// 735.533 us; speedup vs baseline: 1.3445x; 1.2943x over previous
//
#include <hip/hip_runtime.h>
#include <math.h>

#define NN 20000
#define NP 20480   // padded to 160*128 (full supertile groups)
#define EE 60000
#define BB 512
#define HC 1024
#define HH 4
#define CC 256

typedef _Float16 f16;
typedef f16 half8 __attribute__((ext_vector_type(8)));
typedef f16 f16x4 __attribute__((ext_vector_type(4)));
typedef float floatx4 __attribute__((ext_vector_type(4)));

__device__ __forceinline__ void load_lds16(const void* g, void* l) {
    __builtin_amdgcn_global_load_lds((const __attribute__((address_space(1))) void*)g,
                                     (__attribute__((address_space(3))) void*)l, 16, 0, 0);
}

// ---------------- precompute kernels ----------------
__global__ void ea_sum_kernel(const float* __restrict__ ea, float* sums, int E_) {
    float s0 = 0.f, s1 = 0.f, s2 = 0.f;
    for (int e = blockIdx.x * 256 + threadIdx.x; e < E_; e += gridDim.x * 256) {
        s0 += ea[e * 3 + 0];
        s1 += ea[e * 3 + 1];
        s2 += ea[e * 3 + 2];
    }
    for (int o = 32; o; o >>= 1) {
        s0 += __shfl_down(s0, o);
        s1 += __shfl_down(s1, o);
        s2 += __shfl_down(s2, o);
    }
    if ((threadIdx.x & 63) == 0) {
        atomicAdd(&sums[0], s0);
        atomicAdd(&sums[1], s1);
        atomicAdd(&sums[2], s2);
    }
}

__global__ void hist_kernel(const int* __restrict__ ei, int* counts, int E_) {
    int e = blockIdx.x * 256 + threadIdx.x;
    if (e < E_) atomicAdd(&counts[ei[E_ + e]], 1);
}

__global__ void scan_kernel(const int* __restrict__ counts, int* indptr, int n) {
    __shared__ int sdata[1024];
    int t = threadIdx.x;
    int carry = 0;
    if (t == 0) indptr[0] = 0;
    for (int base = 0; base < n; base += 1024) {
        int i = base + t;
        int v = (i < n) ? counts[i] : 0;
        sdata[t] = v;
        __syncthreads();
        for (int off = 1; off < 1024; off <<= 1) {
            int tmp = (t >= off) ? sdata[t - off] : 0;
            __syncthreads();
            sdata[t] += tmp;
            __syncthreads();
        }
        if (i < n) indptr[i + 1] = carry + sdata[t];
        int total = sdata[1023];
        __syncthreads();
        carry += total;
    }
}

__global__ void scatter_kernel(const int* __restrict__ ei, const int* __restrict__ indptr,
                               int* fill, int* sorted, int E_) {
    int e = blockIdx.x * 256 + threadIdx.x;
    if (e >= E_) return;
    int d = ei[E_ + e];
    int pos = indptr[d] + atomicAdd(&fill[d], 1);
    sorted[pos] = e;
}

__global__ void bptr_kernel(const int* __restrict__ batch, int* bptr, int n, int nb) {
    int i = blockIdx.x * 256 + threadIdx.x;
    if (i >= n) return;
    int b = batch[i];
    if (i == 0) {
        for (int bb = 0; bb <= b; bb++) bptr[bb] = 0;
    } else {
        int pb = batch[i - 1];
        if (pb != b) {
            for (int bb = pb + 1; bb <= b; bb++) bptr[bb] = i;
        }
    }
    if (i == n - 1) {
        for (int bb = b + 1; bb <= nb; bb++) bptr[bb] = n;
    }
}

// transpose+convert w_rest[3][1024][1024] fp32 -> wt[3][n][k] fp16 (B^T)
__global__ void wconv_kernel(const float* __restrict__ w_rest, f16* __restrict__ wt) {
    __shared__ float tile[64][65];
    int l = blockIdx.z;
    int bx = blockIdx.x * 64;
    int by = blockIdx.y * 64;
    int t = threadIdx.x;
    int tr = t >> 6, tc = t & 63;
#pragma unroll
    for (int i = 0; i < 16; i++) {
        int r = by + i * 4 + tr;
        tile[i * 4 + tr][tc] = w_rest[(size_t)l * 1048576 + (size_t)r * 1024 + bx + tc];
    }
    __syncthreads();
#pragma unroll
    for (int i = 0; i < 16; i++) {
        int n = bx + i * 4 + tr;
        wt[(size_t)l * 1048576 + (size_t)n * 1024 + by + tc] = (f16)tile[tc][i * 4 + tr];
    }
}

// Mmat[l][d][h]; ae_self[l][h]
__global__ void mmat_all_kernel(const float* __restrict__ w_edge,
                                const float* __restrict__ att_edge,
                                const float* __restrict__ ea_sums, float* Mmat,
                                float* ae_self, float invE) {
    __shared__ float red[256];
    __shared__ float Ms[12];
    int l = blockIdx.x;
    int t = threadIdx.x;
    for (int dh = 0; dh < 12; dh++) {
        int d = dh >> 2, hh = dh & 3;
        float v = w_edge[l * 3072 + d * HC + hh * CC + t] * att_edge[l * HC + hh * CC + t];
        red[t] = v;
        __syncthreads();
        for (int o = 128; o; o >>= 1) {
            if (t < o) red[t] += red[t + o];
            __syncthreads();
        }
        if (t == 0) {
            Ms[dh] = red[0];
            Mmat[l * 12 + dh] = red[0];
        }
        __syncthreads();
    }
    if (t < 4) {
        float v = 0.f;
        for (int d = 0; d < 3; d++) v += ea_sums[d] * invE * Ms[d * 4 + t];
        ae_self[l * 4 + t] = v;
    }
}

// pack CSR: ssrc[idx] = src node; aeh_pk[idx][l][h] = ea[eid]·M[l][:,h]
__global__ void pack_kernel(const int* __restrict__ ei, const int* __restrict__ sorted,
                            const float* __restrict__ ea, const float* __restrict__ Mmat,
                            int* __restrict__ ssrc, float* __restrict__ aeh_pk) {
    int idx = blockIdx.x * 256 + threadIdx.x;
    if (idx >= EE) return;
    int eid = sorted[idx];
    ssrc[idx] = ei[eid];
    float a0 = ea[eid * 3 + 0], a1 = ea[eid * 3 + 1], a2 = ea[eid * 3 + 2];
#pragma unroll
    for (int l = 0; l < 4; l++) {
#pragma unroll
        for (int h = 0; h < 4; h++) {
            aeh_pk[(size_t)idx * 16 + l * 4 + h] =
                a0 * Mmat[l * 12 + h] + a1 * Mmat[l * 12 + 4 + h] + a2 * Mmat[l * 12 + 8 + h];
        }
    }
}

// per-layer edge-parallel: q[idx][h] = asrc[src][h] + aeh_pk[idx][layer][h]
__global__ void edgep_kernel(const int* __restrict__ ssrc, const float* __restrict__ aeh_pk,
                             const float* __restrict__ asrc, float* __restrict__ q,
                             int layer) {
    int i = blockIdx.x * 256 + threadIdx.x;
    if (i >= EE) return;
    int src = ssrc[i];
    float4 a = *(const float4*)&asrc[(size_t)src * 4];
    float4 m = *(const float4*)&aeh_pk[(size_t)i * 16 + layer * 4];
    float4 o;
    o.x = a.x + m.x;
    o.y = a.y + m.y;
    o.z = a.z + m.z;
    o.w = a.w + m.w;
    *(float4*)&q[(size_t)i * 4] = o;
}

// fold bias+BN into 2 params: out = relu(val*scale + shift)
__global__ void bnss_kernel(const float* __restrict__ bias012, const float* __restrict__ bn_g,
                            const float* __restrict__ bn_b, const float* __restrict__ bn_m,
                            const float* __restrict__ bn_v, float2* __restrict__ bnss) {
    int i = blockIdx.x * 256 + threadIdx.x;
    if (i >= 3 * HC) return;
    float s = bn_g[i] * rsqrtf(bn_v[i] + 1e-5f);
    float2 o;
    o.x = s;
    o.y = (bias012[i] - bn_m[i]) * s + bn_b[i];
    bnss[i] = o;
}

// wsv/wdv[l][k][hp]
__global__ void wvec_kernel(const float* __restrict__ w_rest, const float* __restrict__ att_src,
                            const float* __restrict__ att_dst, float* __restrict__ wsv,
                            float* __restrict__ wdv) {
    int l = blockIdx.y;
    int k = blockIdx.x;
    int t = threadIdx.x;
    int hp = t >> 6, lane = t & 63;
    int col = hp * 256 + lane * 4;
    const float* wrow = w_rest + (size_t)l * 1048576 + (size_t)k * 1024;
    float4 w4 = *(const float4*)&wrow[col];
    float4 a4 = *(const float4*)&att_src[(l + 1) * HC + col];
    float4 d4 = *(const float4*)&att_dst[(l + 1) * HC + col];
    float sp = w4.x * a4.x + w4.y * a4.y + w4.z * a4.z + w4.w * a4.w;
    float dp = w4.x * d4.x + w4.y * d4.y + w4.z * d4.z + w4.w * d4.w;
    for (int m = 1; m < 64; m <<= 1) {
        sp += __shfl_xor(sp, m);
        dp += __shfl_xor(dp, m);
    }
    if (lane == 0) {
        wsv[((size_t)l * 1024 + k) * 4 + hp] = sp;
        wdv[((size_t)l * 1024 + k) * 4 + hp] = dp;
    }
}

__global__ void w0vec_kernel(const float* __restrict__ w0, const float* __restrict__ att_src,
                             const float* __restrict__ att_dst, float* __restrict__ w0s,
                             float* __restrict__ w0d) {
    int f = blockIdx.x;
    int t = threadIdx.x;
    int hp = t >> 6, lane = t & 63;
    int col = hp * 256 + lane * 4;
    float4 w4 = *(const float4*)&w0[f * HC + col];
    float4 a4 = *(const float4*)&att_src[col];
    float4 d4 = *(const float4*)&att_dst[col];
    float sp = w4.x * a4.x + w4.y * a4.y + w4.z * a4.z + w4.w * a4.w;
    float dp = w4.x * d4.x + w4.y * d4.y + w4.z * d4.z + w4.w * d4.w;
    for (int m = 1; m < 64; m <<= 1) {
        sp += __shfl_xor(sp, m);
        dp += __shfl_xor(dp, m);
    }
    if (lane == 0) {
        w0s[f * 4 + hp] = sp;
        w0d[f * 4 + hp] = dp;
    }
}

__global__ void alpha0_kernel(const float* __restrict__ x, const float* __restrict__ w0s,
                              const float* __restrict__ w0d, float* __restrict__ asrc,
                              float* __restrict__ adst) {
    int n = blockIdx.x * 256 + threadIdx.x;
    if (n >= NN) return;
    float xr[7];
#pragma unroll
    for (int f = 0; f < 7; f++) xr[f] = x[n * 7 + f];
#pragma unroll
    for (int hp = 0; hp < 4; hp++) {
        float s = 0.f, d = 0.f;
#pragma unroll
        for (int f = 0; f < 7; f++) {
            s += xr[f] * w0s[f * 4 + hp];
            d += xr[f] * w0d[f * 4 + hp];
        }
        asrc[n * 4 + hp] = s;
        adst[n * 4 + hp] = d;
    }
}

// ---------------- layer 0 (commuted: aggregate x first, then @ w0) ----------------
// xagg[n][h][7] = (1/denom) * (p_self*x[n] + sum_e pe*x[src]) per head. 28B/edge gather.
__global__ void agg0x_kernel(const float* __restrict__ x, const float* __restrict__ asrc,
                             const float* __restrict__ adst, const float* __restrict__ ae_self,
                             const int* __restrict__ ssrc, const float* __restrict__ q,
                             const int* __restrict__ indptr, float* __restrict__ xagg) {
    int n = blockIdx.x * 256 + threadIdx.x;
    if (n >= NN) return;
    float4 as4 = *(const float4*)&asrc[(size_t)n * 4];
    float4 ad4 = *(const float4*)&adst[(size_t)n * 4];
    float adl[4] = {ad4.x, ad4.y, ad4.z, ad4.w};
    float asl[4] = {as4.x, as4.y, as4.z, as4.w};
    float xr[7];
#pragma unroll
    for (int f = 0; f < 7; f++) xr[f] = x[n * 7 + f];
    float denom[4];
    float xa[4][7];
#pragma unroll
    for (int h = 0; h < 4; h++) {
        float r = asl[h] + adl[h] + ae_self[h];
        r = (r > 0.f) ? r : 0.2f * r;
        float p = __expf(r);
        denom[h] = p;
#pragma unroll
        for (int f = 0; f < 7; f++) xa[h][f] = p * xr[f];
    }
    int s = indptr[n], e = indptr[n + 1];
    for (int idx = s; idx < e; idx++) {
        int src = ssrc[idx];
        float4 qv = *(const float4*)&q[(size_t)idx * 4];
        float ql[4] = {qv.x, qv.y, qv.z, qv.w};
        float xs[7];
#pragma unroll
        for (int f = 0; f < 7; f++) xs[f] = x[src * 7 + f];
#pragma unroll
        for (int h = 0; h < 4; h++) {
            float rr = ql[h] + adl[h];
            rr = (rr > 0.f) ? rr : 0.2f * rr;
            float pe = __expf(rr);
            denom[h] += pe;
#pragma unroll
            for (int f = 0; f < 7; f++) xa[h][f] += pe * xs[f];
        }
    }
#pragma unroll
    for (int h = 0; h < 4; h++) {
        float inv = 1.0f / (denom[h] + 1e-16f);
#pragma unroll
        for (int f = 0; f < 7; f++) xagg[(size_t)n * 28 + h * 7 + f] = xa[h][f] * inv;
    }
}

// h_act[n] = relu(BN(xagg[n] @ w0)) (fp16) + next-layer asrc/adst epilogue.
__global__ void gemm7f_kernel(const float* __restrict__ xagg, const float* __restrict__ w0,
                              const float2* __restrict__ bnss, const float* __restrict__ wsv,
                              const float* __restrict__ wdv, f16* __restrict__ out16,
                              float* __restrict__ asrc_n, float* __restrict__ adst_n) {
    __shared__ float xs[28];
    __shared__ float red[32];
    int n = blockIdx.x, t = threadIdx.x;
    if (t < 28) xs[t] = xagg[(size_t)n * 28 + t];
    __syncthreads();
    float sp[4] = {0.f, 0.f, 0.f, 0.f}, dp[4] = {0.f, 0.f, 0.f, 0.f};
#pragma unroll
    for (int k = 0; k < 4; k++) {
        int j = k * 256 + t;
        float dot = 0.f;
#pragma unroll
        for (int f = 0; f < 7; f++) dot += xs[k * 7 + f] * w0[f * HC + j];
        float2 ss = bnss[j];
        float val = fmaxf(fmaf(dot, ss.x, ss.y), 0.f);
        out16[(size_t)n * HC + j] = (f16)val;
        float4 w4s = *(const float4*)&wsv[(size_t)j * 4];
        float4 w4d = *(const float4*)&wdv[(size_t)j * 4];
        sp[0] += val * w4s.x; sp[1] += val * w4s.y;
        sp[2] += val * w4s.z; sp[3] += val * w4s.w;
        dp[0] += val * w4d.x; dp[1] += val * w4d.y;
        dp[2] += val * w4d.z; dp[3] += val * w4d.w;
    }
    int wave = t >> 6, lane = t & 63;
#pragma unroll
    for (int m = 1; m < 64; m <<= 1) {
#pragma unroll
        for (int j = 0; j < 4; j++) {
            sp[j] += __shfl_xor(sp[j], m);
            dp[j] += __shfl_xor(dp[j], m);
        }
    }
    if (lane == 0) {
#pragma unroll
        for (int j = 0; j < 4; j++) {
            red[wave * 8 + j] = sp[j];
            red[wave * 8 + 4 + j] = dp[j];
        }
    }
    __syncthreads();
    if (t < 8) {
        float v = red[t] + red[8 + t] + red[16 + t] + red[24 + t];
        if (t < 4) asrc_n[n * 4 + t] = v;
        else adst_n[n * 4 + (t - 4)] = v;
    }
}

// ---------------- GEMM (layers 1-3) ----------------
// C16 = A @ Bt^T, M=NP padded (no predicates), BK=32/16KB LDS, operand-swapped
// epilogue (8B packed stores). 1D grid with L2 supertile: groups of 8 m-blocks x 8
// n-blocks (~4MB working set) so A is HBM-fetched ~once.
__global__ __launch_bounds__(256) void mfma_gemm_kernel(const f16* __restrict__ A,
                                                        const f16* __restrict__ Bt,
                                                        f16* __restrict__ C16,
                                                        int N, int K) {
    __shared__ f16 As[4 * 128 * 8];
    __shared__ f16 Bs[4 * 128 * 8];
    int t = threadIdx.x;
    int wave = t >> 6, lane = t & 63;
    int wr = (wave >> 1) * 64;
    int wc = (wave & 1) * 64;
    int gid = blockIdx.x;
    int g = gid >> 6;
    int rblk = gid & 63;
    int n0 = (rblk >> 3) * 128;
    int m0 = (g * 8 + (rblk & 7)) * 128;

    floatx4 acc[4][4];
#pragma unroll
    for (int i = 0; i < 4; i++)
#pragma unroll
        for (int j = 0; j < 4; j++) acc[i][j] = (floatx4){0.f, 0.f, 0.f, 0.f};

    int q0 = t >> 7, r0 = t & 127;
    int q1 = (256 + t) >> 7, r1 = (256 + t) & 127;
    const f16* pa0 = A + (size_t)(m0 + r0) * K + q0 * 8;
    const f16* pa1 = A + (size_t)(m0 + r1) * K + q1 * 8;
    const f16* pb0 = Bt + (size_t)(n0 + r0) * K + q0 * 8;
    const f16* pb1 = Bt + (size_t)(n0 + r1) * K + q1 * 8;
    f16* la0 = As + (size_t)t * 8;
    f16* la1 = As + (size_t)(256 + t) * 8;
    f16* lb0 = Bs + (size_t)t * 8;
    f16* lb1 = Bs + (size_t)(256 + t) * 8;

    int fq = lane >> 4, fr = lane & 15;
    int aoff[4], boff[4];
#pragma unroll
    for (int i = 0; i < 4; i++) {
        aoff[i] = (fq * 128 + wr + i * 16 + fr) * 8;
        boff[i] = (fq * 128 + wc + i * 16 + fr) * 8;
    }

    for (int k0 = 0; k0 < K; k0 += 32) {
        __syncthreads();
        load_lds16(pa0 + k0, la0);
        load_lds16(pa1 + k0, la1);
        load_lds16(pb0 + k0, lb0);
        load_lds16(pb1 + k0, lb1);
        __syncthreads();
        half8 af[4], bf[4];
#pragma unroll
        for (int i = 0; i < 4; i++) af[i] = *(const half8*)&As[aoff[i]];
#pragma unroll
        for (int j = 0; j < 4; j++) bf[j] = *(const half8*)&Bs[boff[j]];
#pragma unroll
        for (int i = 0; i < 4; i++)
#pragma unroll
            for (int j = 0; j < 4; j++)
                acc[i][j] = __builtin_amdgcn_mfma_f32_16x16x32_f16(bf[j], af[i], acc[i][j],
                                                                   0, 0, 0);
    }

    int rr = lane & 15, cq = lane >> 4;
#pragma unroll
    for (int i = 0; i < 4; i++) {
        int row = m0 + wr + i * 16 + rr;
#pragma unroll
        for (int j = 0; j < 4; j++) {
            f16x4 o;
#pragma unroll
            for (int r = 0; r < 4; r++) o[r] = (f16)acc[i][j][r];
            *(f16x4*)&C16[(size_t)row * N + n0 + wc + j * 16 + cq * 4] = o;
        }
    }
}

// ---------------- fused attention + aggregation (block per node, layers 1-3) -------
__global__ void agg_kernel(const f16* __restrict__ h16, const float* __restrict__ asrc,
                           const float* __restrict__ adst, const float* __restrict__ ae_self,
                           const int* __restrict__ ssrc, const float* __restrict__ q,
                           const int* __restrict__ indptr, const float2* __restrict__ bnss,
                           const float* __restrict__ wsv, const float* __restrict__ wdv,
                           const float* __restrict__ bias3, f16* __restrict__ out16,
                           float* __restrict__ asrc_n, float* __restrict__ adst_n,
                           float* __restrict__ out3, int layer, int concat) {
    __shared__ float buf[1024];
    __shared__ float red[32];
    int n = blockIdx.x, t = threadIdx.x;
    int h = t >> 6, lane = t & 63;
    int c4 = t * 4;

    float adst_nh = adst[n * 4 + h];
    float r = asrc[n * 4 + h] + adst_nh + ae_self[layer * 4 + h];
    r = (r > 0.f) ? r : 0.2f * r;
    float p = __expf(r);
    float denom = p;
    float ax, ay, az, aw;
    {
        f16x4 v = *(const f16x4*)&h16[(size_t)n * HC + c4];
        ax = p * (float)v[0]; ay = p * (float)v[1];
        az = p * (float)v[2]; aw = p * (float)v[3];
    }
    int s = indptr[n], epos = indptr[n + 1];
    for (int base = s; base < epos; base += 2) {
        int s0 = ssrc[base];
        float q0 = q[(size_t)base * 4 + h];
        int has1 = (base + 1 < epos);
        int s1 = has1 ? ssrc[base + 1] : n;
        float q1 = has1 ? q[(size_t)(base + 1) * 4 + h] : -1e9f;
        f16x4 u0 = *(const f16x4*)&h16[(size_t)s0 * HC + c4];
        f16x4 u1 = *(const f16x4*)&h16[(size_t)s1 * HC + c4];
        float r0 = q0 + adst_nh;
        r0 = (r0 > 0.f) ? r0 : 0.2f * r0;
        float p0 = __expf(r0);
        float r1 = q1 + adst_nh;
        r1 = (r1 > 0.f) ? r1 : 0.2f * r1;
        float p1 = __expf(r1);
        denom += p0 + p1;
        ax += p0 * (float)u0[0] + p1 * (float)u1[0];
        ay += p0 * (float)u0[1] + p1 * (float)u1[1];
        az += p0 * (float)u0[2] + p1 * (float)u1[2];
        aw += p0 * (float)u0[3] + p1 * (float)u1[3];
    }
    float inv = 1.0f / (denom + 1e-16f);
    ax *= inv; ay *= inv; az *= inv; aw *= inv;

    if (concat) {
        float vals[4] = {ax, ay, az, aw};
        f16x4 o;
        float sp[4] = {0.f, 0.f, 0.f, 0.f}, dp[4] = {0.f, 0.f, 0.f, 0.f};
#pragma unroll
        for (int k = 0; k < 4; k++) {
            int j = c4 + k;
            float2 ss = bnss[j];
            float val = fmaxf(fmaf(vals[k], ss.x, ss.y), 0.f);
            o[k] = (f16)val;
            float4 w4s = *(const float4*)&wsv[(size_t)j * 4];
            float4 w4d = *(const float4*)&wdv[(size_t)j * 4];
            sp[0] += val * w4s.x; sp[1] += val * w4s.y;
            sp[2] += val * w4s.z; sp[3] += val * w4s.w;
            dp[0] += val * w4d.x; dp[1] += val * w4d.y;
            dp[2] += val * w4d.z; dp[3] += val * w4d.w;
        }
        *(f16x4*)&out16[(size_t)n * HC + c4] = o;
#pragma unroll
        for (int m = 1; m < 64; m <<= 1) {
#pragma unroll
            for (int j = 0; j < 4; j++) {
                sp[j] += __shfl_xor(sp[j], m);
                dp[j] += __shfl_xor(dp[j], m);
            }
        }
        if (lane == 0) {
#pragma unroll
            for (int j = 0; j < 4; j++) {
                red[h * 8 + j] = sp[j];
                red[h * 8 + 4 + j] = dp[j];
            }
        }
        __syncthreads();
        if (t < 8) {
            float v = red[t] + red[8 + t] + red[16 + t] + red[24 + t];
            if (t < 4) asrc_n[n * 4 + t] = v;
            else adst_n[n * 4 + (t - 4)] = v;
        }
    } else {
        buf[c4 + 0] = ax;
        buf[c4 + 1] = ay;
        buf[c4 + 2] = az;
        buf[c4 + 3] = aw;
        __syncthreads();
        if (t < 64) {
#pragma unroll
            for (int k = 0; k < 4; k++) {
                int c = t * 4 + k;
                float v2 = 0.25f * (buf[c] + buf[256 + c] + buf[512 + c] + buf[768 + c]) +
                           bias3[c];
                out3[(size_t)n * CC + c] = v2;
            }
        }
    }
}

// ---------------- readout ----------------
__global__ void gate_kernel(const float* __restrict__ h3, const float* __restrict__ gw,
                            const float* __restrict__ gb, float* gate) {
    int node = blockIdx.x * 4 + (threadIdx.x >> 6);
    int lane = threadIdx.x & 63;
    if (node >= NN) return;
    const float4 hv = *(const float4*)&h3[(size_t)node * CC + lane * 4];
    const float4 w4 = *(const float4*)&gw[lane * 4];
    float s = hv.x * w4.x + hv.y * w4.y + hv.z * w4.z + hv.w * w4.w;
    for (int o = 32; o; o >>= 1) s += __shfl_down(s, o);
    if (lane == 0) gate[node] = s + gb[0];
}

__global__ void graphagg_kernel(const float* __restrict__ gate, const float* __restrict__ h3,
                                const int* __restrict__ bptr, float* __restrict__ graph) {
    __shared__ float red[256];
    __shared__ float wn[256];
    int b = blockIdx.x, t = threadIdx.x;
    int s = bptr[b], epos = bptr[b + 1];
    float m = -3.4e38f;
    for (int n = s + t; n < epos; n += 256) m = fmaxf(m, gate[n]);
    red[t] = m;
    __syncthreads();
    for (int o = 128; o; o >>= 1) {
        if (t < o) red[t] = fmaxf(red[t], red[t + o]);
        __syncthreads();
    }
    float mval = red[0];
    __syncthreads();
    float sum = 0.f;
    for (int n = s + t; n < epos; n += 256) sum += __expf(gate[n] - mval);
    red[t] = sum;
    __syncthreads();
    for (int o = 128; o; o >>= 1) {
        if (t < o) red[t] += red[t + o];
        __syncthreads();
    }
    float ssum = red[0];
    __syncthreads();
    float acc = 0.f;
    for (int base = s; base < epos; base += 256) {
        int n = base + t;
        wn[t] = (n < epos) ? __expf(gate[n] - mval) : 0.f;
        __syncthreads();
        int cnt = min(256, epos - base);
        for (int j = 0; j < cnt; j++) acc += wn[j] * h3[(size_t)(base + j) * CC + t];
        __syncthreads();
    }
    graph[b * CC + t] = acc / (ssum + 1e-16f);
}

__global__ void proj_kernel(const float* __restrict__ graph, const float* __restrict__ pw,
                            const float* __restrict__ pb, float* __restrict__ out) {
    __shared__ float g[256];
    int b = blockIdx.x, t = threadIdx.x;
    g[t] = graph[b * CC + t];
    __syncthreads();
    for (int j = t; j < 1024; j += 256) {
        float acc = pb[j];
        for (int c = 0; c < 256; c++) acc += g[c] * pw[c * 1024 + j];
        out[(size_t)b * 1024 + j] = acc;
    }
}

// ---------------- host ----------------
extern "C" void kernel_launch(void* const* d_in, const int* in_sizes, int n_in,
                              void* d_out, int out_size, void* d_ws, size_t ws_size,
                              hipStream_t stream) {
    const float* x = (const float*)d_in[0];
    const int* ei = (const int*)d_in[1];
    const float* ea = (const float*)d_in[2];
    const int* batch = (const int*)d_in[3];
    const float* w0 = (const float*)d_in[4];
    const float* w_rest = (const float*)d_in[5];
    const float* w_edge = (const float*)d_in[6];
    const float* att_src = (const float*)d_in[7];
    const float* att_dst = (const float*)d_in[8];
    const float* att_edge = (const float*)d_in[9];
    const float* bias012 = (const float*)d_in[10];
    const float* bias3 = (const float*)d_in[11];
    const float* bn_g = (const float*)d_in[12];
    const float* bn_b = (const float*)d_in[13];
    const float* bn_m = (const float*)d_in[14];
    const float* bn_v = (const float*)d_in[15];
    const float* gate_w = (const float*)d_in[16];
    const float* gate_b = (const float*)d_in[17];
    const float* proj_w = (const float*)d_in[18];
    const float* proj_b = (const float*)d_in[19];
    float* out = (float*)d_out;

    float* ws = (float*)d_ws;
    size_t off = 0;
    f16* h_lin = (f16*)(ws + off); off += (size_t)NP * HC / 2;
    f16* h_in = (f16*)(ws + off); off += (size_t)NP * HC / 2;
    float* h3 = ws + off; off += (size_t)NN * CC;
    f16* wt = (f16*)(ws + off); off += (size_t)3 * HC * HC / 2;
    float* asrcA = ws + off; off += (size_t)NN * 4;
    float* adstA = ws + off; off += (size_t)NN * 4;
    float* asrcB = ws + off; off += (size_t)NN * 4;
    float* adstB = ws + off; off += (size_t)NN * 4;
    float* wsv = ws + off; off += (size_t)3 * HC * 4;
    float* wdv = ws + off; off += (size_t)3 * HC * 4;
    float* w0s = ws + off; off += 28;
    float* w0d = ws + off; off += 28;
    float2* bnss = (float2*)(ws + off); off += (size_t)3 * HC * 2;
    float* aeh_pk = ws + off; off += (size_t)EE * 16;
    float* qbuf = ws + off; off += (size_t)EE * 4;
    float* xagg = ws + off; off += (size_t)NN * 28;
    float* gate = ws + off; off += (size_t)NN;
    float* graph = ws + off; off += (size_t)BB * CC;
    float* ea_sums = ws + off; off += 4;
    float* Mmat = ws + off; off += 48;
    float* ae_self = ws + off; off += 16;
    int* counts = (int*)(ws + off); off += NN;
    int* indptr = (int*)(ws + off); off += NN + 1;
    int* fill = (int*)(ws + off); off += NN;
    int* sorted = (int*)(ws + off); off += EE;
    int* ssrc = (int*)(ws + off); off += EE;
    int* bptr = (int*)(ws + off); off += BB + 1;

    hipMemsetAsync(ea_sums, 0, 4 * sizeof(float), stream);
    hipMemsetAsync(counts, 0, NN * sizeof(int), stream);
    hipMemsetAsync(fill, 0, NN * sizeof(int), stream);

    ea_sum_kernel<<<64, 256, 0, stream>>>(ea, ea_sums, EE);
    hist_kernel<<<(EE + 255) / 256, 256, 0, stream>>>(ei, counts, EE);
    scan_kernel<<<1, 1024, 0, stream>>>(counts, indptr, NN);
    scatter_kernel<<<(EE + 255) / 256, 256, 0, stream>>>(ei, indptr, fill, sorted, EE);
    bptr_kernel<<<(NN + 255) / 256, 256, 0, stream>>>(batch, bptr, NN, BB);
    wconv_kernel<<<dim3(16, 16, 3), 256, 0, stream>>>(w_rest, wt);
    mmat_all_kernel<<<4, 256, 0, stream>>>(w_edge, att_edge, ea_sums, Mmat, ae_self,
                                           1.0f / EE);
    pack_kernel<<<(EE + 255) / 256, 256, 0, stream>>>(ei, sorted, ea, Mmat, ssrc, aeh_pk);
    bnss_kernel<<<(3 * HC + 255) / 256, 256, 0, stream>>>(bias012, bn_g, bn_b, bn_m, bn_v,
                                                          bnss);
    wvec_kernel<<<dim3(1024, 3), 256, 0, stream>>>(w_rest, att_src, att_dst, wsv, wdv);
    w0vec_kernel<<<7, 256, 0, stream>>>(w0, att_src, att_dst, w0s, w0d);
    alpha0_kernel<<<(NN + 255) / 256, 256, 0, stream>>>(x, w0s, w0d, asrcA, adstA);

    // ---- layer 0 (commuted) ----
    edgep_kernel<<<(EE + 255) / 256, 256, 0, stream>>>(ssrc, aeh_pk, asrcA, qbuf, 0);
    agg0x_kernel<<<(NN + 255) / 256, 256, 0, stream>>>(x, asrcA, adstA, ae_self, ssrc,
                                                       qbuf, indptr, xagg);
    gemm7f_kernel<<<NN, 256, 0, stream>>>(xagg, w0, bnss, wsv, wdv, h_in, asrcB, adstB);

    float* asrc_cur = asrcB;
    float* adst_cur = adstB;
    float* asrc_nxt = asrcA;
    float* adst_nxt = adstA;
    for (int i = 1; i < 4; i++) {
        mfma_gemm_kernel<<<(NP / 128) * (HC / 128), 256, 0, stream>>>(
            h_in, wt + (size_t)(i - 1) * HC * HC, h_lin, HC, HC);
        edgep_kernel<<<(EE + 255) / 256, 256, 0, stream>>>(ssrc, aeh_pk, asrc_cur, qbuf, i);
        agg_kernel<<<NN, 256, 0, stream>>>(
            h_lin, asrc_cur, adst_cur, ae_self, ssrc, qbuf, indptr, bnss + (size_t)i * HC,
            wsv + (size_t)i * HC * 4, wdv + (size_t)i * HC * 4, bias3, h_in, asrc_nxt,
            adst_nxt, h3, i, (i < 3) ? 1 : 0);
        float* tmp = asrc_cur; asrc_cur = asrc_nxt; asrc_nxt = tmp;
        tmp = adst_cur; adst_cur = adst_nxt; adst_nxt = tmp;
    }

    gate_kernel<<<(NN + 3) / 4, 256, 0, stream>>>(h3, gate_w, gate_b, gate);
    graphagg_kernel<<<BB, 256, 0, stream>>>(gate, h3, bptr, graph);
    proj_kernel<<<BB, 256, 0, stream>>>(graph, proj_w, proj_b, out);
}

// Round 8
// 696.811 us; speedup vs baseline: 1.4193x; 1.0556x over previous
//
#include <hip/hip_runtime.h>
#include <math.h>

#define NN 20000
#define NP 20480   // padded to 160*128 (full supertile groups)
#define EE 60000
#define BB 512
#define HC 1024
#define HH 4
#define CC 256

typedef _Float16 f16;
typedef f16 half8 __attribute__((ext_vector_type(8)));
typedef f16 f16x4 __attribute__((ext_vector_type(4)));
typedef float floatx4 __attribute__((ext_vector_type(4)));
typedef float floatx16 __attribute__((ext_vector_type(16)));

__device__ __forceinline__ void load_lds16(const void* g, void* l) {
    __builtin_amdgcn_global_load_lds((const __attribute__((address_space(1))) void*)g,
                                     (__attribute__((address_space(3))) void*)l, 16, 0, 0);
}

// ---------------- precompute kernels ----------------
__global__ void ea_sum_kernel(const float* __restrict__ ea, float* sums, int E_) {
    float s0 = 0.f, s1 = 0.f, s2 = 0.f;
    for (int e = blockIdx.x * 256 + threadIdx.x; e < E_; e += gridDim.x * 256) {
        s0 += ea[e * 3 + 0];
        s1 += ea[e * 3 + 1];
        s2 += ea[e * 3 + 2];
    }
    for (int o = 32; o; o >>= 1) {
        s0 += __shfl_down(s0, o);
        s1 += __shfl_down(s1, o);
        s2 += __shfl_down(s2, o);
    }
    if ((threadIdx.x & 63) == 0) {
        atomicAdd(&sums[0], s0);
        atomicAdd(&sums[1], s1);
        atomicAdd(&sums[2], s2);
    }
}

__global__ void hist_kernel(const int* __restrict__ ei, int* counts, int E_) {
    int e = blockIdx.x * 256 + threadIdx.x;
    if (e < E_) atomicAdd(&counts[ei[E_ + e]], 1);
}

// two-level scan: (1) per-block inclusive scan + block sums
__global__ void scan1_kernel(const int* __restrict__ counts, int* __restrict__ partial,
                             int* __restrict__ psums, int n) {
    __shared__ int sdata[256];
    int t = threadIdx.x;
    int i = blockIdx.x * 256 + t;
    int v = (i < n) ? counts[i] : 0;
    sdata[t] = v;
    __syncthreads();
#pragma unroll
    for (int off = 1; off < 256; off <<= 1) {
        int tmp = (t >= off) ? sdata[t - off] : 0;
        __syncthreads();
        sdata[t] += tmp;
        __syncthreads();
    }
    if (i < n) partial[i] = sdata[t];
    if (t == 255) psums[blockIdx.x] = sdata[255];
}

// (2) scan the block sums -> exclusive offsets (nb <= 128)
__global__ void scan2_kernel(int* __restrict__ psums, int nb) {
    __shared__ int sdata[128];
    int t = threadIdx.x;
    sdata[t] = (t < nb) ? psums[t] : 0;
    __syncthreads();
#pragma unroll
    for (int off = 1; off < 128; off <<= 1) {
        int tmp = (t >= off) ? sdata[t - off] : 0;
        __syncthreads();
        sdata[t] += tmp;
        __syncthreads();
    }
    if (t < nb) psums[t] = (t == 0) ? 0 : sdata[t - 1];
}

// (3) add offsets, write indptr
__global__ void scan3_kernel(const int* __restrict__ partial, const int* __restrict__ psums,
                             int* __restrict__ indptr, int n) {
    int i = blockIdx.x * 256 + threadIdx.x;
    if (i == 0) indptr[0] = 0;
    if (i < n) indptr[i + 1] = partial[i] + psums[blockIdx.x];
}

__global__ void scatter_kernel(const int* __restrict__ ei, const int* __restrict__ indptr,
                               int* fill, int* sorted, int E_) {
    int e = blockIdx.x * 256 + threadIdx.x;
    if (e >= E_) return;
    int d = ei[E_ + e];
    int pos = indptr[d] + atomicAdd(&fill[d], 1);
    sorted[pos] = e;
}

__global__ void bptr_kernel(const int* __restrict__ batch, int* bptr, int n, int nb) {
    int i = blockIdx.x * 256 + threadIdx.x;
    if (i >= n) return;
    int b = batch[i];
    if (i == 0) {
        for (int bb = 0; bb <= b; bb++) bptr[bb] = 0;
    } else {
        int pb = batch[i - 1];
        if (pb != b) {
            for (int bb = pb + 1; bb <= b; bb++) bptr[bb] = i;
        }
    }
    if (i == n - 1) {
        for (int bb = b + 1; bb <= nb; bb++) bptr[bb] = n;
    }
}

// transpose+convert w_rest[3][1024][1024] fp32 -> wt[3][n][k] fp16 (B^T)
__global__ void wconv_kernel(const float* __restrict__ w_rest, f16* __restrict__ wt) {
    __shared__ float tile[64][65];
    int l = blockIdx.z;
    int bx = blockIdx.x * 64;
    int by = blockIdx.y * 64;
    int t = threadIdx.x;
    int tr = t >> 6, tc = t & 63;
#pragma unroll
    for (int i = 0; i < 16; i++) {
        int r = by + i * 4 + tr;
        tile[i * 4 + tr][tc] = w_rest[(size_t)l * 1048576 + (size_t)r * 1024 + bx + tc];
    }
    __syncthreads();
#pragma unroll
    for (int i = 0; i < 16; i++) {
        int n = bx + i * 4 + tr;
        wt[(size_t)l * 1048576 + (size_t)n * 1024 + by + tc] = (f16)tile[tc][i * 4 + tr];
    }
}

// Mmat[l][d][h]; ae_self[l][h]
__global__ void mmat_all_kernel(const float* __restrict__ w_edge,
                                const float* __restrict__ att_edge,
                                const float* __restrict__ ea_sums, float* Mmat,
                                float* ae_self, float invE) {
    __shared__ float red[256];
    __shared__ float Ms[12];
    int l = blockIdx.x;
    int t = threadIdx.x;
    for (int dh = 0; dh < 12; dh++) {
        int d = dh >> 2, hh = dh & 3;
        float v = w_edge[l * 3072 + d * HC + hh * CC + t] * att_edge[l * HC + hh * CC + t];
        red[t] = v;
        __syncthreads();
        for (int o = 128; o; o >>= 1) {
            if (t < o) red[t] += red[t + o];
            __syncthreads();
        }
        if (t == 0) {
            Ms[dh] = red[0];
            Mmat[l * 12 + dh] = red[0];
        }
        __syncthreads();
    }
    if (t < 4) {
        float v = 0.f;
        for (int d = 0; d < 3; d++) v += ea_sums[d] * invE * Ms[d * 4 + t];
        ae_self[l * 4 + t] = v;
    }
}

// pack CSR: ssrc[idx] = src node; aeh_pk[idx][l][h] = ea[eid]·M[l][:,h]
__global__ void pack_kernel(const int* __restrict__ ei, const int* __restrict__ sorted,
                            const float* __restrict__ ea, const float* __restrict__ Mmat,
                            int* __restrict__ ssrc, float* __restrict__ aeh_pk) {
    int idx = blockIdx.x * 256 + threadIdx.x;
    if (idx >= EE) return;
    int eid = sorted[idx];
    ssrc[idx] = ei[eid];
    float a0 = ea[eid * 3 + 0], a1 = ea[eid * 3 + 1], a2 = ea[eid * 3 + 2];
#pragma unroll
    for (int l = 0; l < 4; l++) {
#pragma unroll
        for (int h = 0; h < 4; h++) {
            aeh_pk[(size_t)idx * 16 + l * 4 + h] =
                a0 * Mmat[l * 12 + h] + a1 * Mmat[l * 12 + 4 + h] + a2 * Mmat[l * 12 + 8 + h];
        }
    }
}

// per-layer edge-parallel: q[idx][h] = asrc[src][h] + aeh_pk[idx][layer][h]
__global__ void edgep_kernel(const int* __restrict__ ssrc, const float* __restrict__ aeh_pk,
                             const float* __restrict__ asrc, float* __restrict__ q,
                             int layer) {
    int i = blockIdx.x * 256 + threadIdx.x;
    if (i >= EE) return;
    int src = ssrc[i];
    float4 a = *(const float4*)&asrc[(size_t)src * 4];
    float4 m = *(const float4*)&aeh_pk[(size_t)i * 16 + layer * 4];
    float4 o;
    o.x = a.x + m.x;
    o.y = a.y + m.y;
    o.z = a.z + m.z;
    o.w = a.w + m.w;
    *(float4*)&q[(size_t)i * 4] = o;
}

// fold bias+BN into 2 params: out = relu(val*scale + shift)
__global__ void bnss_kernel(const float* __restrict__ bias012, const float* __restrict__ bn_g,
                            const float* __restrict__ bn_b, const float* __restrict__ bn_m,
                            const float* __restrict__ bn_v, float2* __restrict__ bnss) {
    int i = blockIdx.x * 256 + threadIdx.x;
    if (i >= 3 * HC) return;
    float s = bn_g[i] * rsqrtf(bn_v[i] + 1e-5f);
    float2 o;
    o.x = s;
    o.y = (bias012[i] - bn_m[i]) * s + bn_b[i];
    bnss[i] = o;
}

// wsv/wdv[l][k][hp]
__global__ void wvec_kernel(const float* __restrict__ w_rest, const float* __restrict__ att_src,
                            const float* __restrict__ att_dst, float* __restrict__ wsv,
                            float* __restrict__ wdv) {
    int l = blockIdx.y;
    int k = blockIdx.x;
    int t = threadIdx.x;
    int hp = t >> 6, lane = t & 63;
    int col = hp * 256 + lane * 4;
    const float* wrow = w_rest + (size_t)l * 1048576 + (size_t)k * 1024;
    float4 w4 = *(const float4*)&wrow[col];
    float4 a4 = *(const float4*)&att_src[(l + 1) * HC + col];
    float4 d4 = *(const float4*)&att_dst[(l + 1) * HC + col];
    float sp = w4.x * a4.x + w4.y * a4.y + w4.z * a4.z + w4.w * a4.w;
    float dp = w4.x * d4.x + w4.y * d4.y + w4.z * d4.z + w4.w * d4.w;
    for (int m = 1; m < 64; m <<= 1) {
        sp += __shfl_xor(sp, m);
        dp += __shfl_xor(dp, m);
    }
    if (lane == 0) {
        wsv[((size_t)l * 1024 + k) * 4 + hp] = sp;
        wdv[((size_t)l * 1024 + k) * 4 + hp] = dp;
    }
}

__global__ void w0vec_kernel(const float* __restrict__ w0, const float* __restrict__ att_src,
                             const float* __restrict__ att_dst, float* __restrict__ w0s,
                             float* __restrict__ w0d) {
    int f = blockIdx.x;
    int t = threadIdx.x;
    int hp = t >> 6, lane = t & 63;
    int col = hp * 256 + lane * 4;
    float4 w4 = *(const float4*)&w0[f * HC + col];
    float4 a4 = *(const float4*)&att_src[col];
    float4 d4 = *(const float4*)&att_dst[col];
    float sp = w4.x * a4.x + w4.y * a4.y + w4.z * a4.z + w4.w * a4.w;
    float dp = w4.x * d4.x + w4.y * d4.y + w4.z * d4.z + w4.w * d4.w;
    for (int m = 1; m < 64; m <<= 1) {
        sp += __shfl_xor(sp, m);
        dp += __shfl_xor(dp, m);
    }
    if (lane == 0) {
        w0s[f * 4 + hp] = sp;
        w0d[f * 4 + hp] = dp;
    }
}

__global__ void alpha0_kernel(const float* __restrict__ x, const float* __restrict__ w0s,
                              const float* __restrict__ w0d, float* __restrict__ asrc,
                              float* __restrict__ adst) {
    int n = blockIdx.x * 256 + threadIdx.x;
    if (n >= NN) return;
    float xr[7];
#pragma unroll
    for (int f = 0; f < 7; f++) xr[f] = x[n * 7 + f];
#pragma unroll
    for (int hp = 0; hp < 4; hp++) {
        float s = 0.f, d = 0.f;
#pragma unroll
        for (int f = 0; f < 7; f++) {
            s += xr[f] * w0s[f * 4 + hp];
            d += xr[f] * w0d[f * 4 + hp];
        }
        asrc[n * 4 + hp] = s;
        adst[n * 4 + hp] = d;
    }
}

// ---------------- layer 0 (commuted: aggregate x first, then @ w0) ----------------
__global__ void agg0x_kernel(const float* __restrict__ x, const float* __restrict__ asrc,
                             const float* __restrict__ adst, const float* __restrict__ ae_self,
                             const int* __restrict__ ssrc, const float* __restrict__ q,
                             const int* __restrict__ indptr, float* __restrict__ xagg) {
    int n = blockIdx.x * 256 + threadIdx.x;
    if (n >= NN) return;
    float4 as4 = *(const float4*)&asrc[(size_t)n * 4];
    float4 ad4 = *(const float4*)&adst[(size_t)n * 4];
    float adl[4] = {ad4.x, ad4.y, ad4.z, ad4.w};
    float asl[4] = {as4.x, as4.y, as4.z, as4.w};
    float xr[7];
#pragma unroll
    for (int f = 0; f < 7; f++) xr[f] = x[n * 7 + f];
    float denom[4];
    float xa[4][7];
#pragma unroll
    for (int h = 0; h < 4; h++) {
        float r = asl[h] + adl[h] + ae_self[h];
        r = (r > 0.f) ? r : 0.2f * r;
        float p = __expf(r);
        denom[h] = p;
#pragma unroll
        for (int f = 0; f < 7; f++) xa[h][f] = p * xr[f];
    }
    int s = indptr[n], e = indptr[n + 1];
    for (int idx = s; idx < e; idx++) {
        int src = ssrc[idx];
        float4 qv = *(const float4*)&q[(size_t)idx * 4];
        float ql[4] = {qv.x, qv.y, qv.z, qv.w};
        float xs[7];
#pragma unroll
        for (int f = 0; f < 7; f++) xs[f] = x[src * 7 + f];
#pragma unroll
        for (int h = 0; h < 4; h++) {
            float rr = ql[h] + adl[h];
            rr = (rr > 0.f) ? rr : 0.2f * rr;
            float pe = __expf(rr);
            denom[h] += pe;
#pragma unroll
            for (int f = 0; f < 7; f++) xa[h][f] += pe * xs[f];
        }
    }
#pragma unroll
    for (int h = 0; h < 4; h++) {
        float inv = 1.0f / (denom[h] + 1e-16f);
#pragma unroll
        for (int f = 0; f < 7; f++) xagg[(size_t)n * 28 + h * 7 + f] = xa[h][f] * inv;
    }
}

// h_act[n] = relu(BN(xagg[n] @ w0)) (fp16) + next-layer asrc/adst epilogue.
__global__ void gemm7f_kernel(const float* __restrict__ xagg, const float* __restrict__ w0,
                              const float2* __restrict__ bnss, const float* __restrict__ wsv,
                              const float* __restrict__ wdv, f16* __restrict__ out16,
                              float* __restrict__ asrc_n, float* __restrict__ adst_n) {
    __shared__ float xs[28];
    __shared__ float red[32];
    int n = blockIdx.x, t = threadIdx.x;
    if (t < 28) xs[t] = xagg[(size_t)n * 28 + t];
    __syncthreads();
    float sp[4] = {0.f, 0.f, 0.f, 0.f}, dp[4] = {0.f, 0.f, 0.f, 0.f};
#pragma unroll
    for (int k = 0; k < 4; k++) {
        int j = k * 256 + t;
        float dot = 0.f;
#pragma unroll
        for (int f = 0; f < 7; f++) dot += xs[k * 7 + f] * w0[f * HC + j];
        float2 ss = bnss[j];
        float val = fmaxf(fmaf(dot, ss.x, ss.y), 0.f);
        out16[(size_t)n * HC + j] = (f16)val;
        float4 w4s = *(const float4*)&wsv[(size_t)j * 4];
        float4 w4d = *(const float4*)&wdv[(size_t)j * 4];
        sp[0] += val * w4s.x; sp[1] += val * w4s.y;
        sp[2] += val * w4s.z; sp[3] += val * w4s.w;
        dp[0] += val * w4d.x; dp[1] += val * w4d.y;
        dp[2] += val * w4d.z; dp[3] += val * w4d.w;
    }
    int wave = t >> 6, lane = t & 63;
#pragma unroll
    for (int m = 1; m < 64; m <<= 1) {
#pragma unroll
        for (int j = 0; j < 4; j++) {
            sp[j] += __shfl_xor(sp[j], m);
            dp[j] += __shfl_xor(dp[j], m);
        }
    }
    if (lane == 0) {
#pragma unroll
        for (int j = 0; j < 4; j++) {
            red[wave * 8 + j] = sp[j];
            red[wave * 8 + 4 + j] = dp[j];
        }
    }
    __syncthreads();
    if (t < 8) {
        float v = red[t] + red[8 + t] + red[16 + t] + red[24 + t];
        if (t < 4) asrc_n[n * 4 + t] = v;
        else adst_n[n * 4 + (t - 4)] = v;
    }
}

// ---------------- GEMM (layers 1-3) ----------------
// C16 = A @ Bt^T, M=NP padded. BK=32/16KB LDS, L2 supertile (8m x 8n groups).
// 32x32x16 MFMA (8 MFMA/K-iter vs 16 for 16x16), operand-swapped epilogue:
// mfma(bf,af) -> D^T: m-row = lane&31, n-cols = (reg&3)+8*(reg>>2)+4*(lane>>5).
__global__ __launch_bounds__(256) void mfma_gemm_kernel(const f16* __restrict__ A,
                                                        const f16* __restrict__ Bt,
                                                        f16* __restrict__ C16,
                                                        int N, int K) {
    __shared__ f16 As[4 * 128 * 8];   // [kgroup8][row][8]
    __shared__ f16 Bs[4 * 128 * 8];
    int t = threadIdx.x;
    int wave = t >> 6, lane = t & 63;
    int wr = (wave >> 1) * 64;
    int wc = (wave & 1) * 64;
    int gid = blockIdx.x;
    int g = gid >> 6;
    int rblk = gid & 63;
    int n0 = (rblk >> 3) * 128;
    int m0 = (g * 8 + (rblk & 7)) * 128;

    floatx16 acc[2][2];
#pragma unroll
    for (int i = 0; i < 2; i++)
#pragma unroll
        for (int j = 0; j < 2; j++) acc[i][j] = (floatx16)(0.f);

    int q0 = t >> 7, r0 = t & 127;
    int q1 = (256 + t) >> 7, r1 = (256 + t) & 127;
    const f16* pa0 = A + (size_t)(m0 + r0) * K + q0 * 8;
    const f16* pa1 = A + (size_t)(m0 + r1) * K + q1 * 8;
    const f16* pb0 = Bt + (size_t)(n0 + r0) * K + q0 * 8;
    const f16* pb1 = Bt + (size_t)(n0 + r1) * K + q1 * 8;
    f16* la0 = As + (size_t)t * 8;
    f16* la1 = As + (size_t)(256 + t) * 8;
    f16* lb0 = Bs + (size_t)t * 8;
    f16* lb1 = Bs + (size_t)(256 + t) * 8;

    int fr32 = lane & 31, kg = lane >> 5;

    for (int k0 = 0; k0 < K; k0 += 32) {
        __syncthreads();
        load_lds16(pa0 + k0, la0);
        load_lds16(pa1 + k0, la1);
        load_lds16(pb0 + k0, lb0);
        load_lds16(pb1 + k0, lb1);
        __syncthreads();
#pragma unroll
        for (int kh = 0; kh < 2; kh++) {
            half8 af[2], bf[2];
#pragma unroll
            for (int i = 0; i < 2; i++)
                af[i] = *(const half8*)&As[((kh * 2 + kg) * 128 + wr + i * 32 + fr32) * 8];
#pragma unroll
            for (int j = 0; j < 2; j++)
                bf[j] = *(const half8*)&Bs[((kh * 2 + kg) * 128 + wc + j * 32 + fr32) * 8];
#pragma unroll
            for (int i = 0; i < 2; i++)
#pragma unroll
                for (int j = 0; j < 2; j++)
                    acc[i][j] = __builtin_amdgcn_mfma_f32_32x32x16_f16(bf[j], af[i],
                                                                       acc[i][j], 0, 0, 0);
        }
    }

#pragma unroll
    for (int i = 0; i < 2; i++) {
        int row = m0 + wr + i * 32 + fr32;
#pragma unroll
        for (int j = 0; j < 2; j++) {
#pragma unroll
            for (int gq = 0; gq < 4; gq++) {
                f16x4 o;
#pragma unroll
                for (int r = 0; r < 4; r++) o[r] = (f16)acc[i][j][gq * 4 + r];
                *(f16x4*)&C16[(size_t)row * N + n0 + wc + j * 32 + gq * 8 + kg * 4] = o;
            }
        }
    }
}

// ---------------- fused attention + aggregation (block per node, chunk-4) ----------
__global__ void agg_kernel(const f16* __restrict__ h16, const float* __restrict__ asrc,
                           const float* __restrict__ adst, const float* __restrict__ ae_self,
                           const int* __restrict__ ssrc, const float* __restrict__ q,
                           const int* __restrict__ indptr, const float2* __restrict__ bnss,
                           const float* __restrict__ wsv, const float* __restrict__ wdv,
                           const float* __restrict__ bias3, f16* __restrict__ out16,
                           float* __restrict__ asrc_n, float* __restrict__ adst_n,
                           float* __restrict__ out3, int layer, int concat) {
    __shared__ float buf[1024];
    __shared__ float red[32];
    int n = blockIdx.x, t = threadIdx.x;
    int h = t >> 6, lane = t & 63;
    int c4 = t * 4;

    float adst_nh = adst[n * 4 + h];
    float r = asrc[n * 4 + h] + adst_nh + ae_self[layer * 4 + h];
    r = (r > 0.f) ? r : 0.2f * r;
    float p = __expf(r);
    float denom = p;
    float ax, ay, az, aw;
    {
        f16x4 v = *(const f16x4*)&h16[(size_t)n * HC + c4];
        ax = p * (float)v[0]; ay = p * (float)v[1];
        az = p * (float)v[2]; aw = p * (float)v[3];
    }
    int s = indptr[n], epos = indptr[n + 1];
    for (int base = s; base < epos; base += 4) {
        int rem = epos - base;
        int src[4];
        float qv[4];
#pragma unroll
        for (int j = 0; j < 4; j++) {
            if (j < rem) {
                src[j] = ssrc[base + j];
                qv[j] = q[(size_t)(base + j) * 4 + h];
            } else {
                src[j] = n;
                qv[j] = -1e9f;
            }
        }
        f16x4 u[4];
#pragma unroll
        for (int j = 0; j < 4; j++) u[j] = *(const f16x4*)&h16[(size_t)src[j] * HC + c4];
#pragma unroll
        for (int j = 0; j < 4; j++) {
            float rr = qv[j] + adst_nh;
            rr = (rr > 0.f) ? rr : 0.2f * rr;
            float pe = __expf(rr);
            denom += pe;
            ax += pe * (float)u[j][0];
            ay += pe * (float)u[j][1];
            az += pe * (float)u[j][2];
            aw += pe * (float)u[j][3];
        }
    }
    float inv = 1.0f / (denom + 1e-16f);
    ax *= inv; ay *= inv; az *= inv; aw *= inv;

    if (concat) {
        float vals[4] = {ax, ay, az, aw};
        f16x4 o;
        float sp[4] = {0.f, 0.f, 0.f, 0.f}, dp[4] = {0.f, 0.f, 0.f, 0.f};
#pragma unroll
        for (int k = 0; k < 4; k++) {
            int j = c4 + k;
            float2 ss = bnss[j];
            float val = fmaxf(fmaf(vals[k], ss.x, ss.y), 0.f);
            o[k] = (f16)val;
            float4 w4s = *(const float4*)&wsv[(size_t)j * 4];
            float4 w4d = *(const float4*)&wdv[(size_t)j * 4];
            sp[0] += val * w4s.x; sp[1] += val * w4s.y;
            sp[2] += val * w4s.z; sp[3] += val * w4s.w;
            dp[0] += val * w4d.x; dp[1] += val * w4d.y;
            dp[2] += val * w4d.z; dp[3] += val * w4d.w;
        }
        *(f16x4*)&out16[(size_t)n * HC + c4] = o;
#pragma unroll
        for (int m = 1; m < 64; m <<= 1) {
#pragma unroll
            for (int j = 0; j < 4; j++) {
                sp[j] += __shfl_xor(sp[j], m);
                dp[j] += __shfl_xor(dp[j], m);
            }
        }
        if (lane == 0) {
#pragma unroll
            for (int j = 0; j < 4; j++) {
                red[h * 8 + j] = sp[j];
                red[h * 8 + 4 + j] = dp[j];
            }
        }
        __syncthreads();
        if (t < 8) {
            float v = red[t] + red[8 + t] + red[16 + t] + red[24 + t];
            if (t < 4) asrc_n[n * 4 + t] = v;
            else adst_n[n * 4 + (t - 4)] = v;
        }
    } else {
        buf[c4 + 0] = ax;
        buf[c4 + 1] = ay;
        buf[c4 + 2] = az;
        buf[c4 + 3] = aw;
        __syncthreads();
        if (t < 64) {
#pragma unroll
            for (int k = 0; k < 4; k++) {
                int c = t * 4 + k;
                float v2 = 0.25f * (buf[c] + buf[256 + c] + buf[512 + c] + buf[768 + c]) +
                           bias3[c];
                out3[(size_t)n * CC + c] = v2;
            }
        }
    }
}

// ---------------- readout ----------------
__global__ void gate_kernel(const float* __restrict__ h3, const float* __restrict__ gw,
                            const float* __restrict__ gb, float* gate) {
    int node = blockIdx.x * 4 + (threadIdx.x >> 6);
    int lane = threadIdx.x & 63;
    if (node >= NN) return;
    const float4 hv = *(const float4*)&h3[(size_t)node * CC + lane * 4];
    const float4 w4 = *(const float4*)&gw[lane * 4];
    float s = hv.x * w4.x + hv.y * w4.y + hv.z * w4.z + hv.w * w4.w;
    for (int o = 32; o; o >>= 1) s += __shfl_down(s, o);
    if (lane == 0) gate[node] = s + gb[0];
}

__global__ void graphagg_kernel(const float* __restrict__ gate, const float* __restrict__ h3,
                                const int* __restrict__ bptr, float* __restrict__ graph) {
    __shared__ float red[256];
    __shared__ float wn[256];
    int b = blockIdx.x, t = threadIdx.x;
    int s = bptr[b], epos = bptr[b + 1];
    float m = -3.4e38f;
    for (int n = s + t; n < epos; n += 256) m = fmaxf(m, gate[n]);
    red[t] = m;
    __syncthreads();
    for (int o = 128; o; o >>= 1) {
        if (t < o) red[t] = fmaxf(red[t], red[t + o]);
        __syncthreads();
    }
    float mval = red[0];
    __syncthreads();
    float sum = 0.f;
    for (int n = s + t; n < epos; n += 256) sum += __expf(gate[n] - mval);
    red[t] = sum;
    __syncthreads();
    for (int o = 128; o; o >>= 1) {
        if (t < o) red[t] += red[t + o];
        __syncthreads();
    }
    float ssum = red[0];
    __syncthreads();
    float acc = 0.f;
    for (int base = s; base < epos; base += 256) {
        int n = base + t;
        wn[t] = (n < epos) ? __expf(gate[n] - mval) : 0.f;
        __syncthreads();
        int cnt = min(256, epos - base);
        for (int j = 0; j < cnt; j++) acc += wn[j] * h3[(size_t)(base + j) * CC + t];
        __syncthreads();
    }
    graph[b * CC + t] = acc / (ssum + 1e-16f);
}

__global__ void proj_kernel(const float* __restrict__ graph, const float* __restrict__ pw,
                            const float* __restrict__ pb, float* __restrict__ out) {
    __shared__ float g[256];
    int b = blockIdx.x, t = threadIdx.x;
    g[t] = graph[b * CC + t];
    __syncthreads();
    for (int j = t; j < 1024; j += 256) {
        float acc = pb[j];
        for (int c = 0; c < 256; c++) acc += g[c] * pw[c * 1024 + j];
        out[(size_t)b * 1024 + j] = acc;
    }
}

// ---------------- host ----------------
extern "C" void kernel_launch(void* const* d_in, const int* in_sizes, int n_in,
                              void* d_out, int out_size, void* d_ws, size_t ws_size,
                              hipStream_t stream) {
    const float* x = (const float*)d_in[0];
    const int* ei = (const int*)d_in[1];
    const float* ea = (const float*)d_in[2];
    const int* batch = (const int*)d_in[3];
    const float* w0 = (const float*)d_in[4];
    const float* w_rest = (const float*)d_in[5];
    const float* w_edge = (const float*)d_in[6];
    const float* att_src = (const float*)d_in[7];
    const float* att_dst = (const float*)d_in[8];
    const float* att_edge = (const float*)d_in[9];
    const float* bias012 = (const float*)d_in[10];
    const float* bias3 = (const float*)d_in[11];
    const float* bn_g = (const float*)d_in[12];
    const float* bn_b = (const float*)d_in[13];
    const float* bn_m = (const float*)d_in[14];
    const float* bn_v = (const float*)d_in[15];
    const float* gate_w = (const float*)d_in[16];
    const float* gate_b = (const float*)d_in[17];
    const float* proj_w = (const float*)d_in[18];
    const float* proj_b = (const float*)d_in[19];
    float* out = (float*)d_out;

    float* ws = (float*)d_ws;
    size_t off = 0;
    f16* h_lin = (f16*)(ws + off); off += (size_t)NP * HC / 2;
    f16* h_in = (f16*)(ws + off); off += (size_t)NP * HC / 2;
    float* h3 = ws + off; off += (size_t)NN * CC;
    f16* wt = (f16*)(ws + off); off += (size_t)3 * HC * HC / 2;
    float* asrcA = ws + off; off += (size_t)NN * 4;
    float* adstA = ws + off; off += (size_t)NN * 4;
    float* asrcB = ws + off; off += (size_t)NN * 4;
    float* adstB = ws + off; off += (size_t)NN * 4;
    float* wsv = ws + off; off += (size_t)3 * HC * 4;
    float* wdv = ws + off; off += (size_t)3 * HC * 4;
    float* w0s = ws + off; off += 28;
    float* w0d = ws + off; off += 28;
    float2* bnss = (float2*)(ws + off); off += (size_t)3 * HC * 2;
    float* aeh_pk = ws + off; off += (size_t)EE * 16;
    float* qbuf = ws + off; off += (size_t)EE * 4;
    float* xagg = ws + off; off += (size_t)NN * 28;
    float* gate = ws + off; off += (size_t)NN;
    float* graph = ws + off; off += (size_t)BB * CC;
    float* ea_sums = ws + off; off += 4;
    float* Mmat = ws + off; off += 48;
    float* ae_self = ws + off; off += 16;
    int* counts = (int*)(ws + off); off += NN;
    int* partial = (int*)(ws + off); off += NN;
    int* psums = (int*)(ws + off); off += 128;
    int* indptr = (int*)(ws + off); off += NN + 1;
    int* fill = (int*)(ws + off); off += NN;
    int* sorted = (int*)(ws + off); off += EE;
    int* ssrc = (int*)(ws + off); off += EE;
    int* bptr = (int*)(ws + off); off += BB + 1;

    hipMemsetAsync(ea_sums, 0, 4 * sizeof(float), stream);
    hipMemsetAsync(counts, 0, NN * sizeof(int), stream);
    hipMemsetAsync(fill, 0, NN * sizeof(int), stream);

    ea_sum_kernel<<<64, 256, 0, stream>>>(ea, ea_sums, EE);
    hist_kernel<<<(EE + 255) / 256, 256, 0, stream>>>(ei, counts, EE);
    int nblk = (NN + 255) / 256;  // 79
    scan1_kernel<<<nblk, 256, 0, stream>>>(counts, partial, psums, NN);
    scan2_kernel<<<1, 128, 0, stream>>>(psums, nblk);
    scan3_kernel<<<nblk, 256, 0, stream>>>(partial, psums, indptr, NN);
    scatter_kernel<<<(EE + 255) / 256, 256, 0, stream>>>(ei, indptr, fill, sorted, EE);
    bptr_kernel<<<(NN + 255) / 256, 256, 0, stream>>>(batch, bptr, NN, BB);
    wconv_kernel<<<dim3(16, 16, 3), 256, 0, stream>>>(w_rest, wt);
    mmat_all_kernel<<<4, 256, 0, stream>>>(w_edge, att_edge, ea_sums, Mmat, ae_self,
                                           1.0f / EE);
    pack_kernel<<<(EE + 255) / 256, 256, 0, stream>>>(ei, sorted, ea, Mmat, ssrc, aeh_pk);
    bnss_kernel<<<(3 * HC + 255) / 256, 256, 0, stream>>>(bias012, bn_g, bn_b, bn_m, bn_v,
                                                          bnss);
    wvec_kernel<<<dim3(1024, 3), 256, 0, stream>>>(w_rest, att_src, att_dst, wsv, wdv);
    w0vec_kernel<<<7, 256, 0, stream>>>(w0, att_src, att_dst, w0s, w0d);
    alpha0_kernel<<<(NN + 255) / 256, 256, 0, stream>>>(x, w0s, w0d, asrcA, adstA);

    // ---- layer 0 (commuted) ----
    edgep_kernel<<<(EE + 255) / 256, 256, 0, stream>>>(ssrc, aeh_pk, asrcA, qbuf, 0);
    agg0x_kernel<<<(NN + 255) / 256, 256, 0, stream>>>(x, asrcA, adstA, ae_self, ssrc,
                                                       qbuf, indptr, xagg);
    gemm7f_kernel<<<NN, 256, 0, stream>>>(xagg, w0, bnss, wsv, wdv, h_in, asrcB, adstB);

    float* asrc_cur = asrcB;
    float* adst_cur = adstB;
    float* asrc_nxt = asrcA;
    float* adst_nxt = adstA;
    for (int i = 1; i < 4; i++) {
        mfma_gemm_kernel<<<(NP / 128) * (HC / 128), 256, 0, stream>>>(
            h_in, wt + (size_t)(i - 1) * HC * HC, h_lin, HC, HC);
        edgep_kernel<<<(EE + 255) / 256, 256, 0, stream>>>(ssrc, aeh_pk, asrc_cur, qbuf, i);
        agg_kernel<<<NN, 256, 0, stream>>>(
            h_lin, asrc_cur, adst_cur, ae_self, ssrc, qbuf, indptr, bnss + (size_t)i * HC,
            wsv + (size_t)i * HC * 4, wdv + (size_t)i * HC * 4, bias3, h_in, asrc_nxt,
            adst_nxt, h3, i, (i < 3) ? 1 : 0);
        float* tmp = asrc_cur; asrc_cur = asrc_nxt; asrc_nxt = tmp;
        tmp = adst_cur; adst_cur = adst_nxt; adst_nxt = tmp;
    }

    gate_kernel<<<(NN + 3) / 4, 256, 0, stream>>>(h3, gate_w, gate_b, gate);
    graphagg_kernel<<<BB, 256, 0, stream>>>(gate, h3, bptr, graph);
    proj_kernel<<<BB, 256, 0, stream>>>(graph, proj_w, proj_b, out);
}